// Round 3
// baseline (620.714 us; speedup 1.0000x reference)
//
#include <hip/hip_runtime.h>
#include <stdint.h>

#define H_ 16
#define DH_ 128
#define RK_ 512
#define RD_ 64
#define B_ 2
#define L_ 2048
#define E_ 2048
#define DQ_ 192            // DH+RD
#define NQ_ (H_*DQ_)       // 3072
#define NKV_ 576
#define NKVP_ 640
#define QKVP_ 3840         // fused q/kv projection width, padded to 15*256
#define NUP_ (H_*(2*DH_+RD_)) // 5120
#define M_ (B_*L_)         // 4096

typedef unsigned short u16;
typedef __bf16 bf16x8 __attribute__((ext_vector_type(8)));
typedef float floatx4 __attribute__((ext_vector_type(4)));

__device__ __forceinline__ u16 f2bf(float f) {
    union { float f; uint32_t u; } v; v.f = f;
    uint32_t u = v.u;
    u = (u + 0x7fffu + ((u >> 16) & 1u)) >> 16;
    return (u16)u;
}
__device__ __forceinline__ float bf2f(u16 b) {
    union { uint32_t u; float f; } v; v.u = ((uint32_t)b) << 16; return v.f;
}

__device__ __forceinline__ void gld_lds16(const void* g, void* l) {
    __builtin_amdgcn_global_load_lds((__attribute__((address_space(1))) void*)(g),
                                     (__attribute__((address_space(3))) void*)(l),
                                     16, 0, 0);
}

// ---------------- fp32 -> bf16 elementwise (x) ----------------
__global__ void convert_bf16(const float* __restrict__ in, u16* __restrict__ out, int n4) {
    int i = blockIdx.x * blockDim.x + threadIdx.x;
    if (i >= n4) return;
    float4 v = ((const float4*)in)[i];
    uint2 o;
    o.x = (uint32_t)f2bf(v.x) | ((uint32_t)f2bf(v.y) << 16);
    o.y = (uint32_t)f2bf(v.z) | ((uint32_t)f2bf(v.w) << 16);
    ((uint2*)out)[i] = o;
}

// ---------------- W (KxN fp32) -> Wt (Npad x K bf16), zero pad ----------------
__global__ void transpose_w(const float* __restrict__ W, u16* __restrict__ Wt,
                            int K, int N, int Npad) {
    __shared__ float tile[32][33];
    int n0 = blockIdx.x * 32, k0 = blockIdx.y * 32;
    int tx = threadIdx.x, ty = threadIdx.y; // 32 x 8
    for (int i = 0; i < 4; i++) {
        int k = k0 + ty + i * 8, n = n0 + tx;
        tile[ty + i * 8][tx] = (n < N) ? W[(size_t)k * N + n] : 0.f;
    }
    __syncthreads();
    for (int i = 0; i < 4; i++) {
        int n = n0 + ty + i * 8, k = k0 + tx;
        Wt[(size_t)n * K + k] = f2bf(tile[tx][ty + i * 8]);
    }
}

// ---------------- 128-tile GEMM (kept for the up-projection: good occupancy at N=5120) ----------------
__global__ __launch_bounds__(256) void gemm_bt(const u16* __restrict__ A,
                                               const u16* __restrict__ Bt,
                                               float* __restrict__ C,
                                               int M, int N, int K) {
    __shared__ __align__(16) u16 As[128 * 32];
    __shared__ __align__(16) u16 Bs[128 * 32];
    const int tid = threadIdx.x;
    const int wave = tid >> 6, lane = tid & 63;
    const int quad = lane >> 4, l16 = lane & 15;
    const int m0 = blockIdx.y * 128, n0 = blockIdx.x * 128;
    const int wm = (wave >> 1) * 64, wn = (wave & 1) * 64;

    floatx4 zero4 = {0.f, 0.f, 0.f, 0.f};
    floatx4 acc[4][4];
    for (int i = 0; i < 4; i++) for (int j = 0; j < 4; j++) acc[i][j] = zero4;

    const u16* Ab = A + (size_t)m0 * K;
    const u16* Bb = Bt + (size_t)n0 * K;

    for (int k0 = 0; k0 < K; k0 += 32) {
        for (int it = 0; it < 2; ++it) {
            int c = it * 256 + tid;
            int row = c >> 2, cr = c & 3;
            gld_lds16(Ab + (size_t)row * K + k0 + cr * 8, As + c * 8);
            gld_lds16(Bb + (size_t)row * K + k0 + cr * 8, Bs + c * 8);
        }
        __syncthreads();
        bf16x8 af[4], bfr[4];
        for (int i = 0; i < 4; i++) af[i]  = *(const bf16x8*)(As + (wm + i * 16 + l16) * 32 + quad * 8);
        for (int j = 0; j < 4; j++) bfr[j] = *(const bf16x8*)(Bs + (wn + j * 16 + l16) * 32 + quad * 8);
        for (int i = 0; i < 4; i++)
            for (int j = 0; j < 4; j++)
                acc[i][j] = __builtin_amdgcn_mfma_f32_16x16x32_bf16(af[i], bfr[j], acc[i][j], 0, 0, 0);
        __syncthreads();
    }
    for (int i = 0; i < 4; i++)
        for (int j = 0; j < 4; j++) {
            int mrow = m0 + wm + i * 16 + quad * 4;
            int ncol = n0 + wn + j * 16 + l16;
            float* Cp = C + (size_t)mrow * N + ncol;
            for (int r = 0; r < 4; r++) Cp[(size_t)r * N] = acc[i][j][r];
        }
}

// ---------------- 256x256 GEMM, BK=32, TRIPLE-buffered LDS, counted vmcnt ----------------
// Race-free depth-2 pipeline: tile t reads buf[t%3]; stage of tile t+2 targets
// buf[(t+2)%3] == buffer retired at end of tile t-1 (its end-barrier precedes the
// stage issue in every wave). Steady-state s_waitcnt vmcnt(8) keeps 8 loads in
// flight across barriers (T4); never drains to 0 mid-loop.
// LDS swizzle (T2): slot (row,b) holds global 16B-block b ^ ((row>>1)&3); the
// read offset folds to a per-lane constant qsw. 16 lanes of a fragment read then
// cover all 8 (row-parity x block) bank windows exactly twice -> 2-way (free).
// Requires: M % 256 == 0 == N % 256, K % 32 == 0, K/32 >= 3, gridDim.y == 16.
__global__ __launch_bounds__(512, 2) void gemm256(const u16* __restrict__ A,
                                                  const u16* __restrict__ Bt,
                                                  float* __restrict__ C,
                                                  int M, int N, int K) {
    __shared__ __align__(16) u16 As[3][256 * 32];
    __shared__ __align__(16) u16 Bs[3][256 * 32];
    const int tid = threadIdx.x;
    const int wave = tid >> 6, lane = tid & 63;
    const int quad = lane >> 4, l16 = lane & 15;
    const int wm = (wave >> 2) * 128, wn = (wave & 3) * 64;

    // XCD-aware bijective swizzle (m204), bx-major so same-B-panel blocks share an XCD
    int nwg = gridDim.x * gridDim.y;
    int flat = blockIdx.y * gridDim.x + blockIdx.x;
    int q = nwg >> 3, r = nwg & 7;
    int xcd = flat & 7, pos = flat >> 3;
    int wg = (xcd < r) ? xcd * (q + 1) + pos : r * (q + 1) + (xcd - r) * q + pos;
    const int m0 = (wg & 15) * 256;          // gridDim.y == 16 (M = 4096)
    const int n0 = (wg >> 4) * 256;

    const u16* Ab = A + (size_t)m0 * K;
    const u16* Bb = Bt + (size_t)n0 * K;

    const int srow = tid >> 2;                                  // 0..127
    const int sblk = (((tid & 3) ^ ((tid >> 3) & 3))) * 8;      // swizzled global block
    const int sdst = srow * 32 + (tid & 3) * 8;                 // linear LDS slot
    const int qsw  = (quad ^ ((l16 >> 1) & 3)) * 8;             // swizzled read offset

    floatx4 zero4 = {0.f, 0.f, 0.f, 0.f};
    floatx4 acc[8][4];
#pragma unroll
    for (int i = 0; i < 8; i++)
#pragma unroll
        for (int j = 0; j < 4; j++) acc[i][j] = zero4;

    auto stage = [&](int t, int b) {
        const u16* Ak = Ab + t * 32;
        const u16* Bk = Bb + t * 32;
        gld_lds16(Ak + (size_t)srow * K + sblk,         As[b] + sdst);
        gld_lds16(Ak + (size_t)(srow + 128) * K + sblk, As[b] + sdst + 128 * 32);
        gld_lds16(Bk + (size_t)srow * K + sblk,         Bs[b] + sdst);
        gld_lds16(Bk + (size_t)(srow + 128) * K + sblk, Bs[b] + sdst + 128 * 32);
    };

    const int NT = K >> 5;
    stage(0, 0);
    stage(1, 1);
    int rb = 0;
    for (int t = 0; t < NT; ++t) {
        if (t + 2 < NT) {
            stage(t + 2, rb ? rb - 1 : 2);   // (rb+2)%3: buffer retired at t-1
            asm volatile("s_waitcnt vmcnt(8)" ::: "memory");   // tile t's 4+ oldest done
        } else if (t + 1 < NT) {
            asm volatile("s_waitcnt vmcnt(4)" ::: "memory");
        } else {
            asm volatile("s_waitcnt vmcnt(0)" ::: "memory");
        }
        __builtin_amdgcn_s_barrier();        // all waves' tile-t loads landed

        const u16* Ar = As[rb];
        const u16* Br = Bs[rb];
        bf16x8 af[8], bfv[4];
#pragma unroll
        for (int i = 0; i < 8; i++) af[i]  = *(const bf16x8*)(Ar + (wm + i * 16 + l16) * 32 + qsw);
#pragma unroll
        for (int j = 0; j < 4; j++) bfv[j] = *(const bf16x8*)(Br + (wn + j * 16 + l16) * 32 + qsw);
        __builtin_amdgcn_s_setprio(1);
#pragma unroll
        for (int i = 0; i < 8; i++)
#pragma unroll
            for (int j = 0; j < 4; j++)
                acc[i][j] = __builtin_amdgcn_mfma_f32_16x16x32_bf16(af[i], bfv[j], acc[i][j], 0, 0, 0);
        __builtin_amdgcn_s_setprio(0);
        __builtin_amdgcn_s_barrier();        // buf[rb] fully read -> may be restaged at t+1
        rb = (rb == 2) ? 0 : rb + 1;
    }

#pragma unroll
    for (int i = 0; i < 8; i++)
#pragma unroll
        for (int j = 0; j < 4; j++) {
            int mrow = m0 + wm + i * 16 + quad * 4;
            int ncol = n0 + wn + j * 16 + l16;
            float* Cp = C + (size_t)mrow * N + ncol;
            for (int rr = 0; rr < 4; rr++) Cp[(size_t)rr * N] = acc[i][j][rr];
        }
}

// ---------------- build q from fused qkv: rope + scale*log2e + layout (B,H,L,192) bf16 ----------------
__global__ void build_q(const float* __restrict__ qkv, const float* __restrict__ cosT,
                        const float* __restrict__ sinT, u16* __restrict__ qb) {
    const float QS = 0.07216878364870323f * 1.4426950408889634f; // 1/sqrt(192) * log2(e)
    int idx = blockIdx.x * blockDim.x + threadIdx.x;
    if (idx >= M_ * H_ * 96) return;
    int p = idx % 96; int t = idx / 96; int h = t % H_; int row = t / H_;
    int l = row & (L_ - 1); int b = row >> 11;
    const float* src = qkv + (size_t)row * QKVP_ + h * DQ_;
    u16* dst = qb + ((size_t)(b * H_ + h) * L_ + l) * DQ_;
    int d = 2 * p;
    float x1 = src[d], x2 = src[d + 1];
    if (d < DH_) { dst[d] = f2bf(x1 * QS); dst[d + 1] = f2bf(x2 * QS); }
    else {
        int i = (d - DH_) >> 1;
        float c = cosT[(size_t)l * 32 + i], s = sinT[(size_t)l * 32 + i];
        dst[d]     = f2bf((x1 * c - x2 * s) * QS);
        dst[d + 1] = f2bf((x1 * s + x2 * c) * QS);
    }
}

// ---------------- build c_kv (bf16) + roped k_rope (bf16) from fused qkv ----------------
__global__ void build_ckv(const float* __restrict__ qkv, const float* __restrict__ cosT,
                          const float* __restrict__ sinT, u16* __restrict__ ckv,
                          u16* __restrict__ kropeb) {
    int idx = blockIdx.x * blockDim.x + threadIdx.x;
    if (idx >= M_ * 288) return;
    int j = idx % 288; int row = idx / 288;
    int l = row & (L_ - 1);
    const float* src = qkv + (size_t)row * QKVP_ + NQ_;
    if (j < 256) {
        ckv[(size_t)row * RK_ + 2 * j]     = f2bf(src[2 * j]);
        ckv[(size_t)row * RK_ + 2 * j + 1] = f2bf(src[2 * j + 1]);
    } else {
        int i = j - 256;
        float x1 = src[RK_ + 2 * i], x2 = src[RK_ + 2 * i + 1];
        float c = cosT[(size_t)l * 32 + i], s = sinT[(size_t)l * 32 + i];
        kropeb[(size_t)row * RD_ + 2 * i]     = f2bf(x1 * c - x2 * s);
        kropeb[(size_t)row * RD_ + 2 * i + 1] = f2bf(x1 * s + x2 * c);
    }
}

// ---------------- build k (B,H,L,192) + vT (B,H,192,L perm) bf16 ----------------
__global__ __launch_bounds__(256) void build_kvt(const float* __restrict__ up,
        const u16* __restrict__ kropeb, u16* __restrict__ kb, u16* __restrict__ vtb) {
    __shared__ float vt[64][193];
    int blk = blockIdx.x;          // (b*H+h)*32 + lt
    int lt = blk & 31; int bh = blk >> 5; int h = bh % H_; int b = bh / H_;
    int tid = threadIdx.x;
    int l0 = lt * 64;
    for (int it = 0; it < 48; ++it) {
        int idx = it * 256 + tid;  // 64*192
        int lr = idx / 192, d = idx % 192;
        size_t row = (size_t)b * L_ + l0 + lr;
        float vv = (d < DH_) ? up[row * NUP_ + h * 320 + DH_ + d]
                             : up[row * NUP_ + h * 320 + 2 * DH_ + (d - DH_)];
        vt[lr][d] = vv;
        u16 kbf = (d < DH_) ? f2bf(up[row * NUP_ + h * 320 + d])
                            : kropeb[row * RD_ + (d - DH_)];
        kb[((size_t)bh * L_ + l0 + lr) * DQ_ + d] = kbf;
    }
    __syncthreads();
    for (int it = 0; it < 48; ++it) {
        int idx = it * 256 + tid;
        int lr = idx & 63, d = idx >> 6;
        int l = l0 + lr;
        int s5 = l & 31;
        int k5 = ((s5 >> 2) & 3) * 8 + ((s5 >> 4) & 1) * 4 + (s5 & 3);
        int lp = (l & ~31) | k5;
        vtb[((size_t)bh * DQ_ + d) * L_ + lp] = f2bf(vt[lr][d]);
    }
}

// ---------------- flash attention, causal, S^T, 512-thread blocks ----------------
__global__ __launch_bounds__(512, 2) void attn(const u16* __restrict__ qb,
        const u16* __restrict__ kb, const u16* __restrict__ vtb,
        u16* __restrict__ po0, u16* __restrict__ po1,
        float* __restrict__ pm0, float* __restrict__ pl0,
        float* __restrict__ pm1, float* __restrict__ pl1) {
    __shared__ __align__(16) u16 Ks[2][64 * 192];
    __shared__ __align__(16) u16 Vs[2][192 * 64];
    int id = blockIdx.x;
    int bh = id & 31, tj = id >> 5;      // same-bh blocks share XCD (id%8 = bh%8)
    int t = tj >> 1, j = tj & 1;
    int tid = threadIdx.x, wave = tid >> 6, lane = tid & 63;
    int quad = lane >> 4, l16 = lane & 15;

    // swizzle lane constants: row&7 == l16&7 for all fragment reads
    const int x7 = l16 & 7;
    const int h2 = (x7 >> 2) & 1;
    const int qx = quad ^ (x7 & 3);
    const int oA = h2 * 32 + qx * 8;        // even kk  / V g=0
    const int oB = (1 - h2) * 32 + qx * 8;  // odd  kk  / V g=1

    u16* po = j ? po1 : po0;
    float* pm = j ? pm1 : pm0;
    float* pl = j ? pl1 : pl0;

    const u16* kbase0 = kb + (size_t)bh * L_ * DQ_;
    const u16* vbase0 = vtb + (size_t)bh * (size_t)DQ_ * L_;
    floatx4 zero4 = {0.f, 0.f, 0.f, 0.f};

    auto stageKV = [&](int st, int buf) {
        const u16* kg = kbase0 + (size_t)st * 64 * DQ_;
        u16* kd = &Ks[buf][0];
        for (int it = 0; it < 3; ++it) {
            int c = it * 512 + tid;          // 0..1535 = 64 rows * 24 blocks
            int s = c / 24, blk = c - s * 24;
            int blog = (blk & 24) | ((blk & 7) ^ (s & 7));
            gld_lds16(kg + (size_t)s * DQ_ + blog * 8, kd + c * 8);
        }
        const u16* vg = vbase0 + st * 64;
        u16* vd = &Vs[buf][0];
        for (int it = 0; it < 3; ++it) {
            int c = it * 512 + tid;          // 0..1535 = 192 rows * 8 blocks
            int d = c >> 3, blk = c & 7;
            int blog = blk ^ (d & 7);
            gld_lds16(vg + (size_t)d * L_ + blog * 8, vd + c * 8);
        }
    };

    for (int seg = 0; seg < 2; ++seg) {
        const int QT = seg == 0 ? (7 - t) : t;
        const int st0 = j ? (2 * QT + 2) : 0;
        const int st1 = j ? (4 * QT + 3) : (2 * QT + 1);

        bf16x8 aq[2][6];
        const u16* qbase = qb + ((size_t)bh * L_ + QT * 256 + wave * 16 + l16) * DQ_;
        for (int a = 0; a < 2; a++)
            for (int kk = 0; kk < 6; kk++)
                aq[a][kk] = *(const bf16x8*)(qbase + a * 128 * DQ_ + kk * 32 + quad * 8);

        floatx4 o[2][12];
        for (int a = 0; a < 2; a++) for (int i = 0; i < 12; i++) o[a][i] = zero4;
        float m_i[2] = {-INFINITY, -INFINITY};
        float l_i[2] = {0.f, 0.f};

        int cur = 0;
        stageKV(st0, 0);   // prologue: 6 loads in flight

        for (int st = st0; st <= st1; ++st) {
            if (st < st1) {
                stageKV(st + 1, cur ^ 1);                      // 6 more loads (12 in flight)
                asm volatile("s_waitcnt vmcnt(6)" ::: "memory"); // oldest 6 (= buf cur) done
            } else {
                asm volatile("s_waitcnt vmcnt(0)" ::: "memory");
            }
            __builtin_amdgcn_s_barrier();   // all waves: buf[cur] fully staged
            const u16* Kc = &Ks[cur][0];
            const u16* Vc = &Vs[cur][0];

            // liveness: R multiple of 16; rowset live iff R >= 0
            int R0 = QT * 256 + wave * 16 - st * 64;
            int R1 = R0 + 128;
            int smax0 = min(3, (R0 + 15) >> 4);
            int smax1 = min(3, (R1 + 15) >> 4);
            bool live0 = smax0 >= 0, live1 = smax1 >= 0;

            float pv[2][4][4];
            float mxa[2] = {-INFINITY, -INFINITY};
#pragma unroll
            for (int stile = 0; stile < 4; ++stile) {
                if (stile > smax1) {
                    for (int r = 0; r < 4; r++) { pv[0][stile][r] = 0.f; pv[1][stile][r] = 0.f; }
                    continue;
                }
                bool do0 = (stile <= smax0);
                floatx4 s1v = zero4, s0v = zero4;
#pragma unroll
                for (int kk = 0; kk < 6; kk++) {
                    int off = (kk >> 1) * 64 + ((kk & 1) ? oB : oA);
                    bf16x8 kf = *(const bf16x8*)(Kc + (stile * 16 + l16) * 192 + off);
                    s1v = __builtin_amdgcn_mfma_f32_16x16x32_bf16(kf, aq[1][kk], s1v, 0, 0, 0);
                    if (do0) s0v = __builtin_amdgcn_mfma_f32_16x16x32_bf16(kf, aq[0][kk], s0v, 0, 0, 0);
                }
                int sb = stile * 16;
                if (sb + 15 > R1) {
                    for (int r = 0; r < 4; r++) {
                        float v = (sb + quad * 4 + r > R1 + l16) ? -1e30f : s1v[r];
                        pv[1][stile][r] = v; mxa[1] = fmaxf(mxa[1], v);
                    }
                } else {
                    for (int r = 0; r < 4; r++) { pv[1][stile][r] = s1v[r]; mxa[1] = fmaxf(mxa[1], s1v[r]); }
                }
                if (do0) {
                    if (sb + 15 > R0) {
                        for (int r = 0; r < 4; r++) {
                            float v = (sb + quad * 4 + r > R0 + l16) ? -1e30f : s0v[r];
                            pv[0][stile][r] = v; mxa[0] = fmaxf(mxa[0], v);
                        }
                    } else {
                        for (int r = 0; r < 4; r++) { pv[0][stile][r] = s0v[r]; mxa[0] = fmaxf(mxa[0], s0v[r]); }
                    }
                } else {
                    for (int r = 0; r < 4; r++) pv[0][stile][r] = 0.f;
                }
            }

            bf16x8 pf[2][2];
            bool lv[2] = {live0, live1};
            int smx[2] = {smax0, smax1};
#pragma unroll
            for (int a = 0; a < 2; a++) {
                if (!lv[a]) continue;
                float mx = mxa[a];
                mx = fmaxf(mx, __shfl_xor(mx, 16));
                mx = fmaxf(mx, __shfl_xor(mx, 32));
                float mn;
                if (__all(mx <= m_i[a] + 8.0f)) {
                    mn = m_i[a];                 // defer-max: keep stale max, no rescale
                } else {
                    mn = fmaxf(m_i[a], mx);
                    float alpha = exp2f(m_i[a] - mn);
                    m_i[a] = mn;
                    l_i[a] *= alpha;
                    for (int i = 0; i < 12; i++) o[a][i] *= alpha;
                }
                float rs = 0.f;
#pragma unroll
                for (int stile = 0; stile < 4; ++stile) {
                    if (stile > smx[a]) continue;
                    for (int r = 0; r < 4; r++) {
                        float e = exp2f(pv[a][stile][r] - mn);
                        pv[a][stile][r] = e;
                        rs += e;
                    }
                }
                rs += __shfl_xor(rs, 16);
                rs += __shfl_xor(rs, 32);
                l_i[a] += rs;
                for (int g = 0; g < 2; g++) {
                    union { bf16x8 v; u16 s[8]; } u;
                    for (int r = 0; r < 4; r++) {
                        u.s[r]     = f2bf(pv[a][g * 2][r]);
                        u.s[4 + r] = f2bf(pv[a][g * 2 + 1][r]);
                    }
                    pf[a][g] = u.v;
                }
            }

            for (int g = 0; g < 2; g++) {
                int vo = g ? oB : oA;
#pragma unroll
                for (int dtile = 0; dtile < 12; dtile++) {
                    bf16x8 vf = *(const bf16x8*)(Vc + (dtile * 16 + l16) * 64 + vo);
                    if (live0)
                        o[0][dtile] = __builtin_amdgcn_mfma_f32_16x16x32_bf16(vf, pf[0][g], o[0][dtile], 0, 0, 0);
                    if (live1)
                        o[1][dtile] = __builtin_amdgcn_mfma_f32_16x16x32_bf16(vf, pf[1][g], o[1][dtile], 0, 0, 0);
                }
            }
            __builtin_amdgcn_s_barrier();   // all waves done reading buf[cur] -> reusable
            cur ^= 1;
        }

        // write partials: po[tile][q 256][d 192] bf16, pm/pl[tile][q 256]
        int tile = bh * 8 + QT;
        for (int a = 0; a < 2; a++) {
            int q = a * 128 + wave * 16 + l16;
            u16* dst = po + ((size_t)tile * 256 + q) * 192;
            for (int dtile = 0; dtile < 12; dtile++) {
                ushort4 pk;
                pk.x = f2bf(o[a][dtile][0]);
                pk.y = f2bf(o[a][dtile][1]);
                pk.z = f2bf(o[a][dtile][2]);
                pk.w = f2bf(o[a][dtile][3]);
                *(ushort4*)(dst + dtile * 16 + quad * 4) = pk;
            }
            if (quad == 0) {
                pm[(size_t)tile * 256 + q] = m_i[a];
                pl[(size_t)tile * 256 + q] = l_i[a];
            }
        }
        __syncthreads();
    }
}

// ---------------- merge the two split-s halves -> ao (B,L,H,192) bf16 ----------------
__global__ void attn_merge(const u16* __restrict__ po0, const u16* __restrict__ po1,
                           const float* __restrict__ pm0, const float* __restrict__ pl0,
                           const float* __restrict__ pm1, const float* __restrict__ pl1,
                           u16* __restrict__ ao) {
    int idx = blockIdx.x * blockDim.x + threadIdx.x;   // 256*256*48
    int c = idx % 48; int rest = idx / 48;
    int q = rest & 255; int tile = rest >> 8;
    int bh = tile >> 3, QT = tile & 7;
    size_t mi = (size_t)tile * 256 + q;
    float m0 = pm0[mi], m1 = pm1[mi];
    float l0 = pl0[mi], l1 = pl1[mi];
    float m = fmaxf(m0, m1);
    float a0 = exp2f(m0 - m), a1 = exp2f(m1 - m);
    float inv = 1.0f / (l0 * a0 + l1 * a1);
    float s0 = a0 * inv, s1 = a1 * inv;
    ushort4 u0 = *(const ushort4*)(po0 + mi * 192 + c * 4);
    ushort4 u1 = *(const ushort4*)(po1 + mi * 192 + c * 4);
    int b = bh >> 4, h = bh & 15;
    int l = QT * 256 + q;
    u16* dst = ao + (((size_t)(b * L_ + l)) * H_ + h) * DQ_ + c * 4;
    ushort4 pk;
    pk.x = f2bf(bf2f(u0.x) * s0 + bf2f(u1.x) * s1);
    pk.y = f2bf(bf2f(u0.y) * s0 + bf2f(u1.y) * s1);
    pk.z = f2bf(bf2f(u0.z) * s0 + bf2f(u1.z) * s1);
    pk.w = f2bf(bf2f(u0.w) * s0 + bf2f(u1.w) * s1);
    *(ushort4*)dst = pk;
}

extern "C" void kernel_launch(void* const* d_in, const int* in_sizes, int n_in,
                              void* d_out, int out_size, void* d_ws, size_t ws_size,
                              hipStream_t stream) {
    const float* x    = (const float*)d_in[0];
    const float* cosT = (const float*)d_in[1];
    const float* sinT = (const float*)d_in[2];
    const float* wq   = (const float*)d_in[3];
    const float* wkv  = (const float*)d_in[4];
    const float* wup  = (const float*)d_in[5];
    const float* wout = (const float*)d_in[6];
    float* out = (float*)d_out;
    char* ws = (char*)d_ws;

    size_t off = 0;
    auto alloc = [&](size_t b) { size_t r = off; off += (b + 255) & ~(size_t)255; return r; };
    u16* xb     = (u16*)(ws + alloc((size_t)M_ * E_ * 2));
    u16* wqkvT  = (u16*)(ws + alloc((size_t)QKVP_ * E_ * 2));   // rows 0..3071 wq^T, 3072..3647 wkv^T, rest 0
    u16* wupT   = (u16*)(ws + alloc((size_t)NUP_ * RK_ * 2));
    u16* woutT  = (u16*)(ws + alloc((size_t)E_ * NQ_ * 2));
    u16* qb     = (u16*)(ws + alloc((size_t)B_ * H_ * L_ * DQ_ * 2));
    u16* kb     = (u16*)(ws + alloc((size_t)B_ * H_ * L_ * DQ_ * 2));
    u16* vtb    = (u16*)(ws + alloc((size_t)B_ * H_ * DQ_ * L_ * 2));
    u16* ao     = (u16*)(ws + alloc((size_t)M_ * NQ_ * 2));
    u16* ckv    = (u16*)(ws + alloc((size_t)M_ * RK_ * 2));
    u16* kropeb = (u16*)(ws + alloc((size_t)M_ * RD_ * 2));
    char* scratch = ws + alloc((size_t)M_ * NUP_ * 4);   // 83.9 MB union region
    float* qkv = (float*)(scratch);                      // M x 3840 fp32 (dead after build_q/build_ckv)
    float* up  = (float*)(scratch);                      // M x 5120 fp32 (dead after build_kvt)
    // attn partials alias scratch (qkv/up all consumed before attn):
    size_t poSz = (size_t)256 * 256 * 192 * 2;                // 25.2 MB each
    u16*   po0 = (u16*)(scratch);
    u16*   po1 = (u16*)(scratch + poSz);
    float* pm0 = (float*)(scratch + 2 * poSz);
    float* pl0 = (float*)(scratch + 2 * poSz + 256 * 256 * 4);
    float* pm1 = (float*)(scratch + 2 * poSz + 2 * 256 * 256 * 4);
    float* pl1 = (float*)(scratch + 2 * poSz + 3 * 256 * 256 * 4);

    dim3 tb(32, 8);
    int n4 = M_ * E_ / 4;
    convert_bf16<<<(n4 + 255) / 256, 256, 0, stream>>>(x, xb, n4);
    transpose_w<<<dim3(NQ_ / 32, E_ / 32), tb, 0, stream>>>(wq, wqkvT, E_, NQ_, NQ_);
    transpose_w<<<dim3((QKVP_ - NQ_) / 32, E_ / 32), tb, 0, stream>>>(wkv, wqkvT + (size_t)NQ_ * E_, E_, NKV_, QKVP_ - NQ_);
    transpose_w<<<dim3(NUP_ / 32, RK_ / 32), tb, 0, stream>>>(wup, wupT, RK_, NUP_, NUP_);
    transpose_w<<<dim3(E_ / 32, NQ_ / 32), tb, 0, stream>>>(wout, woutT, NQ_, E_, E_);

    // fused q+kv projection: 256^2 pipelined GEMM, grid 15x16 = 240 blocks
    gemm256<<<dim3(QKVP_ / 256, M_ / 256), 512, 0, stream>>>(xb, wqkvT, qkv, M_, QKVP_, E_);

    int nq = M_ * H_ * 96;
    build_q<<<(nq + 255) / 256, 256, 0, stream>>>(qkv, cosT, sinT, qb);
    int nc = M_ * 288;
    build_ckv<<<(nc + 255) / 256, 256, 0, stream>>>(qkv, cosT, sinT, ckv, kropeb);

    // up-projection: keep 128^2 (N=5120 -> 1280 blocks, good occupancy; 256^2 would 2-wave-tail)
    gemm_bt<<<dim3(NUP_ / 128, M_ / 128), 256, 0, stream>>>(ckv, wupT, up, M_, NUP_, RK_);
    build_kvt<<<B_ * H_ * 32, 256, 0, stream>>>(up, kropeb, kb, vtb);

    attn<<<256, 512, 0, stream>>>(qb, kb, vtb, po0, po1, pm0, pl0, pm1, pl1);
    attn_merge<<<(256 * 256 * 48) / 256, 256, 0, stream>>>(po0, po1, pm0, pl0, pm1, pl1, ao);

    // output projection: 256^2 GEMM, grid 8x16 = 128 blocks (K=3072 long loop)
    gemm256<<<dim3(E_ / 256, M_ / 256), 512, 0, stream>>>(ao, woutT, out, M_, E_, NQ_);
}

// Round 4
// 584.831 us; speedup vs baseline: 1.0614x; 1.0614x over previous
//
#include <hip/hip_runtime.h>
#include <stdint.h>

#define H_ 16
#define DH_ 128
#define RK_ 512
#define RD_ 64
#define B_ 2
#define L_ 2048
#define E_ 2048
#define DQ_ 192            // DH+RD
#define NQ_ (H_*DQ_)       // 3072
#define NKV_ 576
#define NKVP_ 640
#define QKVP_ 3840         // fused q/kv projection width, padded to 15*256
#define NUP_ (H_*(2*DH_+RD_)) // 5120
#define M_ (B_*L_)         // 4096

typedef unsigned short u16;
typedef __bf16 bf16x8 __attribute__((ext_vector_type(8)));
typedef float floatx4 __attribute__((ext_vector_type(4)));

__device__ __forceinline__ u16 f2bf(float f) {
    union { float f; uint32_t u; } v; v.f = f;
    uint32_t u = v.u;
    u = (u + 0x7fffu + ((u >> 16) & 1u)) >> 16;
    return (u16)u;
}
__device__ __forceinline__ float bf2f(u16 b) {
    union { uint32_t u; float f; } v; v.u = ((uint32_t)b) << 16; return v.f;
}

__device__ __forceinline__ void gld_lds16(const void* g, void* l) {
    __builtin_amdgcn_global_load_lds((__attribute__((address_space(1))) void*)(g),
                                     (__attribute__((address_space(3))) void*)(l),
                                     16, 0, 0);
}

// ---------------- fp32 -> bf16 elementwise (x) ----------------
__global__ void convert_bf16(const float* __restrict__ in, u16* __restrict__ out, int n4) {
    int i = blockIdx.x * blockDim.x + threadIdx.x;
    if (i >= n4) return;
    float4 v = ((const float4*)in)[i];
    uint2 o;
    o.x = (uint32_t)f2bf(v.x) | ((uint32_t)f2bf(v.y) << 16);
    o.y = (uint32_t)f2bf(v.z) | ((uint32_t)f2bf(v.w) << 16);
    ((uint2*)out)[i] = o;
}

// ---------------- W (KxN fp32) -> Wt (Npad x K bf16), zero pad ----------------
__global__ void transpose_w(const float* __restrict__ W, u16* __restrict__ Wt,
                            int K, int N, int Npad) {
    __shared__ float tile[32][33];
    int n0 = blockIdx.x * 32, k0 = blockIdx.y * 32;
    int tx = threadIdx.x, ty = threadIdx.y; // 32 x 8
    for (int i = 0; i < 4; i++) {
        int k = k0 + ty + i * 8, n = n0 + tx;
        tile[ty + i * 8][tx] = (n < N) ? W[(size_t)k * N + n] : 0.f;
    }
    __syncthreads();
    for (int i = 0; i < 4; i++) {
        int n = n0 + ty + i * 8, k = k0 + tx;
        Wt[(size_t)n * K + k] = f2bf(tile[tx][ty + i * 8]);
    }
}

// ---------------- 128-tile GEMM (kept for the up-projection: good occupancy at N=5120) ----------------
__global__ __launch_bounds__(256) void gemm_bt(const u16* __restrict__ A,
                                               const u16* __restrict__ Bt,
                                               float* __restrict__ C,
                                               int M, int N, int K) {
    __shared__ __align__(16) u16 As[128 * 32];
    __shared__ __align__(16) u16 Bs[128 * 32];
    const int tid = threadIdx.x;
    const int wave = tid >> 6, lane = tid & 63;
    const int quad = lane >> 4, l16 = lane & 15;
    const int m0 = blockIdx.y * 128, n0 = blockIdx.x * 128;
    const int wm = (wave >> 1) * 64, wn = (wave & 1) * 64;

    floatx4 zero4 = {0.f, 0.f, 0.f, 0.f};
    floatx4 acc[4][4];
    for (int i = 0; i < 4; i++) for (int j = 0; j < 4; j++) acc[i][j] = zero4;

    const u16* Ab = A + (size_t)m0 * K;
    const u16* Bb = Bt + (size_t)n0 * K;

    for (int k0 = 0; k0 < K; k0 += 32) {
        for (int it = 0; it < 2; ++it) {
            int c = it * 256 + tid;
            int row = c >> 2, cr = c & 3;
            gld_lds16(Ab + (size_t)row * K + k0 + cr * 8, As + c * 8);
            gld_lds16(Bb + (size_t)row * K + k0 + cr * 8, Bs + c * 8);
        }
        __syncthreads();
        bf16x8 af[4], bfr[4];
        for (int i = 0; i < 4; i++) af[i]  = *(const bf16x8*)(As + (wm + i * 16 + l16) * 32 + quad * 8);
        for (int j = 0; j < 4; j++) bfr[j] = *(const bf16x8*)(Bs + (wn + j * 16 + l16) * 32 + quad * 8);
        for (int i = 0; i < 4; i++)
            for (int j = 0; j < 4; j++)
                acc[i][j] = __builtin_amdgcn_mfma_f32_16x16x32_bf16(af[i], bfr[j], acc[i][j], 0, 0, 0);
        __syncthreads();
    }
    for (int i = 0; i < 4; i++)
        for (int j = 0; j < 4; j++) {
            int mrow = m0 + wm + i * 16 + quad * 4;
            int ncol = n0 + wn + j * 16 + l16;
            float* Cp = C + (size_t)mrow * N + ncol;
            for (int r = 0; r < 4; r++) Cp[(size_t)r * N] = acc[i][j][r];
        }
}

// ---------------- 256x128 GEMM, BK=32, TRIPLE-buffered LDS, counted vmcnt ----------------
// Pipeline (race-free by construction): tile t reads buf[t%3]; stage of tile t+2
// targets buf[(t+2)%3] == the buffer retired at end of tile t-1 (its end-barrier
// precedes the stage issue in every wave). 3 loads/thread/stage -> steady-state
// s_waitcnt vmcnt(6); never drains to 0 mid-loop (T4).
// LDS swizzle (T2): slot (row,b) holds global 16B-block b ^ ((row>>1)&3); read
// offset folds to per-lane constant qsw -> 0 bank conflicts (verified round 3).
// 72 KB LDS + launch_bounds(512,4) -> 2 blocks/CU (16 waves/CU) for overlap.
// Requires: M % 256 == 0, N % 128 == 0, K % 32 == 0, K/32 >= 3, gridDim.y == 16.
__global__ __launch_bounds__(512, 4) void gemm256(const u16* __restrict__ A,
                                                  const u16* __restrict__ Bt,
                                                  float* __restrict__ C,
                                                  int M, int N, int K) {
    __shared__ __align__(16) u16 As[3][256 * 32];
    __shared__ __align__(16) u16 Bs[3][128 * 32];
    const int tid = threadIdx.x;
    const int wave = tid >> 6, lane = tid & 63;
    const int quad = lane >> 4, l16 = lane & 15;
    const int wm = (wave >> 1) * 64, wn = (wave & 1) * 64;

    // XCD-aware bijective swizzle (m204), bx-major: consecutive wg share B-panel
    int nwg = gridDim.x * gridDim.y;
    int flat = blockIdx.y * gridDim.x + blockIdx.x;
    int q = nwg >> 3, r = nwg & 7;
    int xcd = flat & 7, pos = flat >> 3;
    int wg = (xcd < r) ? xcd * (q + 1) + pos : r * (q + 1) + (xcd - r) * q + pos;
    const int m0 = (wg & 15) * 256;          // gridDim.y == 16 (M = 4096)
    const int n0 = (wg >> 4) * 128;

    const u16* Ab = A + (size_t)m0 * K;
    const u16* Bb = Bt + (size_t)n0 * K;

    const int qsw = (quad ^ ((l16 >> 1) & 3)) * 8;   // swizzled read offset

    floatx4 zero4 = {0.f, 0.f, 0.f, 0.f};
    floatx4 acc[4][4];
#pragma unroll
    for (int i = 0; i < 4; i++)
#pragma unroll
        for (int j = 0; j < 4; j++) acc[i][j] = zero4;

    auto stage = [&](int t, int b) {
        const u16* Ak = Ab + t * 32;
        const u16* Bk = Bb + t * 32;
#pragma unroll
        for (int it = 0; it < 2; ++it) {             // A: 256 rows x 4 blocks
            int c = it * 512 + tid;
            int row = c >> 2, blk = c & 3;
            int bg = blk ^ ((row >> 1) & 3);
            gld_lds16(Ak + (size_t)row * K + bg * 8, As[b] + row * 32 + blk * 8);
        }
        {                                             // B: 128 rows x 4 blocks
            int row = tid >> 2, blk = tid & 3;
            int bg = blk ^ ((row >> 1) & 3);
            gld_lds16(Bk + (size_t)row * K + bg * 8, Bs[b] + row * 32 + blk * 8);
        }
    };

    const int NT = K >> 5;
    stage(0, 0);
    stage(1, 1);
    int rb = 0;
    for (int t = 0; t < NT; ++t) {
        if (t + 2 < NT) {
            stage(t + 2, rb ? rb - 1 : 2);   // (rb+2)%3: buffer retired at t-1
            asm volatile("s_waitcnt vmcnt(6)" ::: "memory");   // oldest 3 (= tile t) done
        } else if (t + 1 < NT) {
            asm volatile("s_waitcnt vmcnt(3)" ::: "memory");
        } else {
            asm volatile("s_waitcnt vmcnt(0)" ::: "memory");
        }
        __builtin_amdgcn_s_barrier();        // all waves' tile-t loads landed

        const u16* Ar = As[rb];
        const u16* Br = Bs[rb];
        bf16x8 af[4], bfv[4];
#pragma unroll
        for (int i = 0; i < 4; i++) af[i]  = *(const bf16x8*)(Ar + (wm + i * 16 + l16) * 32 + qsw);
#pragma unroll
        for (int j = 0; j < 4; j++) bfv[j] = *(const bf16x8*)(Br + (wn + j * 16 + l16) * 32 + qsw);
        __builtin_amdgcn_s_setprio(1);
#pragma unroll
        for (int i = 0; i < 4; i++)
#pragma unroll
            for (int j = 0; j < 4; j++)
                acc[i][j] = __builtin_amdgcn_mfma_f32_16x16x32_bf16(af[i], bfv[j], acc[i][j], 0, 0, 0);
        __builtin_amdgcn_s_setprio(0);
        __builtin_amdgcn_s_barrier();        // buf[rb] fully read -> may be restaged
        rb = (rb == 2) ? 0 : rb + 1;
    }

#pragma unroll
    for (int i = 0; i < 4; i++)
#pragma unroll
        for (int j = 0; j < 4; j++) {
            int mrow = m0 + wm + i * 16 + quad * 4;
            int ncol = n0 + wn + j * 16 + l16;
            float* Cp = C + (size_t)mrow * N + ncol;
            for (int rr = 0; rr < 4; rr++) Cp[(size_t)rr * N] = acc[i][j][rr];
        }
}

// ---------------- build q from fused qkv: rope + scale*log2e + layout (B,H,L,192) bf16 ----------------
__global__ void build_q(const float* __restrict__ qkv, const float* __restrict__ cosT,
                        const float* __restrict__ sinT, u16* __restrict__ qb) {
    const float QS = 0.07216878364870323f * 1.4426950408889634f; // 1/sqrt(192) * log2(e)
    int idx = blockIdx.x * blockDim.x + threadIdx.x;
    if (idx >= M_ * H_ * 96) return;
    int p = idx % 96; int t = idx / 96; int h = t % H_; int row = t / H_;
    int l = row & (L_ - 1); int b = row >> 11;
    const float* src = qkv + (size_t)row * QKVP_ + h * DQ_;
    u16* dst = qb + ((size_t)(b * H_ + h) * L_ + l) * DQ_;
    int d = 2 * p;
    float x1 = src[d], x2 = src[d + 1];
    if (d < DH_) { dst[d] = f2bf(x1 * QS); dst[d + 1] = f2bf(x2 * QS); }
    else {
        int i = (d - DH_) >> 1;
        float c = cosT[(size_t)l * 32 + i], s = sinT[(size_t)l * 32 + i];
        dst[d]     = f2bf((x1 * c - x2 * s) * QS);
        dst[d + 1] = f2bf((x1 * s + x2 * c) * QS);
    }
}

// ---------------- build c_kv (bf16) + roped k_rope (bf16) from fused qkv ----------------
__global__ void build_ckv(const float* __restrict__ qkv, const float* __restrict__ cosT,
                          const float* __restrict__ sinT, u16* __restrict__ ckv,
                          u16* __restrict__ kropeb) {
    int idx = blockIdx.x * blockDim.x + threadIdx.x;
    if (idx >= M_ * 288) return;
    int j = idx % 288; int row = idx / 288;
    int l = row & (L_ - 1);
    const float* src = qkv + (size_t)row * QKVP_ + NQ_;
    if (j < 256) {
        ckv[(size_t)row * RK_ + 2 * j]     = f2bf(src[2 * j]);
        ckv[(size_t)row * RK_ + 2 * j + 1] = f2bf(src[2 * j + 1]);
    } else {
        int i = j - 256;
        float x1 = src[RK_ + 2 * i], x2 = src[RK_ + 2 * i + 1];
        float c = cosT[(size_t)l * 32 + i], s = sinT[(size_t)l * 32 + i];
        kropeb[(size_t)row * RD_ + 2 * i]     = f2bf(x1 * c - x2 * s);
        kropeb[(size_t)row * RD_ + 2 * i + 1] = f2bf(x1 * s + x2 * c);
    }
}

// ---------------- build k (B,H,L,192) + vT (B,H,192,L perm) bf16 ----------------
__global__ __launch_bounds__(256) void build_kvt(const float* __restrict__ up,
        const u16* __restrict__ kropeb, u16* __restrict__ kb, u16* __restrict__ vtb) {
    __shared__ float vt[64][193];
    int blk = blockIdx.x;          // (b*H+h)*32 + lt
    int lt = blk & 31; int bh = blk >> 5; int h = bh % H_; int b = bh / H_;
    int tid = threadIdx.x;
    int l0 = lt * 64;
    for (int it = 0; it < 48; ++it) {
        int idx = it * 256 + tid;  // 64*192
        int lr = idx / 192, d = idx % 192;
        size_t row = (size_t)b * L_ + l0 + lr;
        float vv = (d < DH_) ? up[row * NUP_ + h * 320 + DH_ + d]
                             : up[row * NUP_ + h * 320 + 2 * DH_ + (d - DH_)];
        vt[lr][d] = vv;
        u16 kbf = (d < DH_) ? f2bf(up[row * NUP_ + h * 320 + d])
                            : kropeb[row * RD_ + (d - DH_)];
        kb[((size_t)bh * L_ + l0 + lr) * DQ_ + d] = kbf;
    }
    __syncthreads();
    for (int it = 0; it < 48; ++it) {
        int idx = it * 256 + tid;
        int lr = idx & 63, d = idx >> 6;
        int l = l0 + lr;
        int s5 = l & 31;
        int k5 = ((s5 >> 2) & 3) * 8 + ((s5 >> 4) & 1) * 4 + (s5 & 3);
        int lp = (l & ~31) | k5;
        vtb[((size_t)bh * DQ_ + d) * L_ + lp] = f2bf(vt[lr][d]);
    }
}

// ---------------- flash attention, causal, S^T, 512-thread blocks ----------------
__global__ __launch_bounds__(512, 2) void attn(const u16* __restrict__ qb,
        const u16* __restrict__ kb, const u16* __restrict__ vtb,
        u16* __restrict__ po0, u16* __restrict__ po1,
        float* __restrict__ pm0, float* __restrict__ pl0,
        float* __restrict__ pm1, float* __restrict__ pl1) {
    __shared__ __align__(16) u16 Ks[2][64 * 192];
    __shared__ __align__(16) u16 Vs[2][192 * 64];
    int id = blockIdx.x;
    int bh = id & 31, tj = id >> 5;      // same-bh blocks share XCD (id%8 = bh%8)
    int t = tj >> 1, j = tj & 1;
    int tid = threadIdx.x, wave = tid >> 6, lane = tid & 63;
    int quad = lane >> 4, l16 = lane & 15;

    // swizzle lane constants: row&7 == l16&7 for all fragment reads
    const int x7 = l16 & 7;
    const int h2 = (x7 >> 2) & 1;
    const int qx = quad ^ (x7 & 3);
    const int oA = h2 * 32 + qx * 8;        // even kk  / V g=0
    const int oB = (1 - h2) * 32 + qx * 8;  // odd  kk  / V g=1

    u16* po = j ? po1 : po0;
    float* pm = j ? pm1 : pm0;
    float* pl = j ? pl1 : pl0;

    const u16* kbase0 = kb + (size_t)bh * L_ * DQ_;
    const u16* vbase0 = vtb + (size_t)bh * (size_t)DQ_ * L_;
    floatx4 zero4 = {0.f, 0.f, 0.f, 0.f};

    auto stageKV = [&](int st, int buf) {
        const u16* kg = kbase0 + (size_t)st * 64 * DQ_;
        u16* kd = &Ks[buf][0];
        for (int it = 0; it < 3; ++it) {
            int c = it * 512 + tid;          // 0..1535 = 64 rows * 24 blocks
            int s = c / 24, blk = c - s * 24;
            int blog = (blk & 24) | ((blk & 7) ^ (s & 7));
            gld_lds16(kg + (size_t)s * DQ_ + blog * 8, kd + c * 8);
        }
        const u16* vg = vbase0 + st * 64;
        u16* vd = &Vs[buf][0];
        for (int it = 0; it < 3; ++it) {
            int c = it * 512 + tid;          // 0..1535 = 192 rows * 8 blocks
            int d = c >> 3, blk = c & 7;
            int blog = blk ^ (d & 7);
            gld_lds16(vg + (size_t)d * L_ + blog * 8, vd + c * 8);
        }
    };

    for (int seg = 0; seg < 2; ++seg) {
        const int QT = seg == 0 ? (7 - t) : t;
        const int st0 = j ? (2 * QT + 2) : 0;
        const int st1 = j ? (4 * QT + 3) : (2 * QT + 1);

        bf16x8 aq[2][6];
        const u16* qbase = qb + ((size_t)bh * L_ + QT * 256 + wave * 16 + l16) * DQ_;
        for (int a = 0; a < 2; a++)
            for (int kk = 0; kk < 6; kk++)
                aq[a][kk] = *(const bf16x8*)(qbase + a * 128 * DQ_ + kk * 32 + quad * 8);

        floatx4 o[2][12];
        for (int a = 0; a < 2; a++) for (int i = 0; i < 12; i++) o[a][i] = zero4;
        float m_i[2] = {-INFINITY, -INFINITY};
        float l_i[2] = {0.f, 0.f};

        int cur = 0;
        stageKV(st0, 0);   // prologue: 6 loads in flight

        for (int st = st0; st <= st1; ++st) {
            if (st < st1) {
                stageKV(st + 1, cur ^ 1);                      // 6 more loads (12 in flight)
                asm volatile("s_waitcnt vmcnt(6)" ::: "memory"); // oldest 6 (= buf cur) done
            } else {
                asm volatile("s_waitcnt vmcnt(0)" ::: "memory");
            }
            __builtin_amdgcn_s_barrier();   // all waves: buf[cur] fully staged
            const u16* Kc = &Ks[cur][0];
            const u16* Vc = &Vs[cur][0];

            // liveness: R multiple of 16; rowset live iff R >= 0
            int R0 = QT * 256 + wave * 16 - st * 64;
            int R1 = R0 + 128;
            int smax0 = min(3, (R0 + 15) >> 4);
            int smax1 = min(3, (R1 + 15) >> 4);
            bool live0 = smax0 >= 0, live1 = smax1 >= 0;

            float pv[2][4][4];
            float mxa[2] = {-INFINITY, -INFINITY};
#pragma unroll
            for (int stile = 0; stile < 4; ++stile) {
                if (stile > smax1) {
                    for (int r = 0; r < 4; r++) { pv[0][stile][r] = 0.f; pv[1][stile][r] = 0.f; }
                    continue;
                }
                bool do0 = (stile <= smax0);
                floatx4 s1v = zero4, s0v = zero4;
#pragma unroll
                for (int kk = 0; kk < 6; kk++) {
                    int off = (kk >> 1) * 64 + ((kk & 1) ? oB : oA);
                    bf16x8 kf = *(const bf16x8*)(Kc + (stile * 16 + l16) * 192 + off);
                    s1v = __builtin_amdgcn_mfma_f32_16x16x32_bf16(kf, aq[1][kk], s1v, 0, 0, 0);
                    if (do0) s0v = __builtin_amdgcn_mfma_f32_16x16x32_bf16(kf, aq[0][kk], s0v, 0, 0, 0);
                }
                int sb = stile * 16;
                if (sb + 15 > R1) {
                    for (int r = 0; r < 4; r++) {
                        float v = (sb + quad * 4 + r > R1 + l16) ? -1e30f : s1v[r];
                        pv[1][stile][r] = v; mxa[1] = fmaxf(mxa[1], v);
                    }
                } else {
                    for (int r = 0; r < 4; r++) { pv[1][stile][r] = s1v[r]; mxa[1] = fmaxf(mxa[1], s1v[r]); }
                }
                if (do0) {
                    if (sb + 15 > R0) {
                        for (int r = 0; r < 4; r++) {
                            float v = (sb + quad * 4 + r > R0 + l16) ? -1e30f : s0v[r];
                            pv[0][stile][r] = v; mxa[0] = fmaxf(mxa[0], v);
                        }
                    } else {
                        for (int r = 0; r < 4; r++) { pv[0][stile][r] = s0v[r]; mxa[0] = fmaxf(mxa[0], s0v[r]); }
                    }
                } else {
                    for (int r = 0; r < 4; r++) pv[0][stile][r] = 0.f;
                }
            }

            bf16x8 pf[2][2];
            bool lv[2] = {live0, live1};
            int smx[2] = {smax0, smax1};
#pragma unroll
            for (int a = 0; a < 2; a++) {
                if (!lv[a]) continue;
                float mx = mxa[a];
                mx = fmaxf(mx, __shfl_xor(mx, 16));
                mx = fmaxf(mx, __shfl_xor(mx, 32));
                float mn;
                if (__all(mx <= m_i[a] + 8.0f)) {
                    mn = m_i[a];                 // defer-max: keep stale max, no rescale
                } else {
                    mn = fmaxf(m_i[a], mx);
                    float alpha = exp2f(m_i[a] - mn);
                    m_i[a] = mn;
                    l_i[a] *= alpha;
                    for (int i = 0; i < 12; i++) o[a][i] *= alpha;
                }
                float rs = 0.f;
#pragma unroll
                for (int stile = 0; stile < 4; ++stile) {
                    if (stile > smx[a]) continue;
                    for (int r = 0; r < 4; r++) {
                        float e = exp2f(pv[a][stile][r] - mn);
                        pv[a][stile][r] = e;
                        rs += e;
                    }
                }
                rs += __shfl_xor(rs, 16);
                rs += __shfl_xor(rs, 32);
                l_i[a] += rs;
                for (int g = 0; g < 2; g++) {
                    union { bf16x8 v; u16 s[8]; } u;
                    for (int r = 0; r < 4; r++) {
                        u.s[r]     = f2bf(pv[a][g * 2][r]);
                        u.s[4 + r] = f2bf(pv[a][g * 2 + 1][r]);
                    }
                    pf[a][g] = u.v;
                }
            }

            for (int g = 0; g < 2; g++) {
                int vo = g ? oB : oA;
#pragma unroll
                for (int dtile = 0; dtile < 12; dtile++) {
                    bf16x8 vf = *(const bf16x8*)(Vc + (dtile * 16 + l16) * 64 + vo);
                    if (live0)
                        o[0][dtile] = __builtin_amdgcn_mfma_f32_16x16x32_bf16(vf, pf[0][g], o[0][dtile], 0, 0, 0);
                    if (live1)
                        o[1][dtile] = __builtin_amdgcn_mfma_f32_16x16x32_bf16(vf, pf[1][g], o[1][dtile], 0, 0, 0);
                }
            }
            __builtin_amdgcn_s_barrier();   // all waves done reading buf[cur] -> reusable
            cur ^= 1;
        }

        // write partials: po[tile][q 256][d 192] bf16, pm/pl[tile][q 256]
        int tile = bh * 8 + QT;
        for (int a = 0; a < 2; a++) {
            int q = a * 128 + wave * 16 + l16;
            u16* dst = po + ((size_t)tile * 256 + q) * 192;
            for (int dtile = 0; dtile < 12; dtile++) {
                ushort4 pk;
                pk.x = f2bf(o[a][dtile][0]);
                pk.y = f2bf(o[a][dtile][1]);
                pk.z = f2bf(o[a][dtile][2]);
                pk.w = f2bf(o[a][dtile][3]);
                *(ushort4*)(dst + dtile * 16 + quad * 4) = pk;
            }
            if (quad == 0) {
                pm[(size_t)tile * 256 + q] = m_i[a];
                pl[(size_t)tile * 256 + q] = l_i[a];
            }
        }
        __syncthreads();
    }
}

// ---------------- merge the two split-s halves -> ao (B,L,H,192) bf16 ----------------
__global__ void attn_merge(const u16* __restrict__ po0, const u16* __restrict__ po1,
                           const float* __restrict__ pm0, const float* __restrict__ pl0,
                           const float* __restrict__ pm1, const float* __restrict__ pl1,
                           u16* __restrict__ ao) {
    int idx = blockIdx.x * blockDim.x + threadIdx.x;   // 256*256*48
    int c = idx % 48; int rest = idx / 48;
    int q = rest & 255; int tile = rest >> 8;
    int bh = tile >> 3, QT = tile & 7;
    size_t mi = (size_t)tile * 256 + q;
    float m0 = pm0[mi], m1 = pm1[mi];
    float l0 = pl0[mi], l1 = pl1[mi];
    float m = fmaxf(m0, m1);
    float a0 = exp2f(m0 - m), a1 = exp2f(m1 - m);
    float inv = 1.0f / (l0 * a0 + l1 * a1);
    float s0 = a0 * inv, s1 = a1 * inv;
    ushort4 u0 = *(const ushort4*)(po0 + mi * 192 + c * 4);
    ushort4 u1 = *(const ushort4*)(po1 + mi * 192 + c * 4);
    int b = bh >> 4, h = bh & 15;
    int l = QT * 256 + q;
    u16* dst = ao + (((size_t)(b * L_ + l)) * H_ + h) * DQ_ + c * 4;
    ushort4 pk;
    pk.x = f2bf(bf2f(u0.x) * s0 + bf2f(u1.x) * s1);
    pk.y = f2bf(bf2f(u0.y) * s0 + bf2f(u1.y) * s1);
    pk.z = f2bf(bf2f(u0.z) * s0 + bf2f(u1.z) * s1);
    pk.w = f2bf(bf2f(u0.w) * s0 + bf2f(u1.w) * s1);
    *(ushort4*)dst = pk;
}

extern "C" void kernel_launch(void* const* d_in, const int* in_sizes, int n_in,
                              void* d_out, int out_size, void* d_ws, size_t ws_size,
                              hipStream_t stream) {
    const float* x    = (const float*)d_in[0];
    const float* cosT = (const float*)d_in[1];
    const float* sinT = (const float*)d_in[2];
    const float* wq   = (const float*)d_in[3];
    const float* wkv  = (const float*)d_in[4];
    const float* wup  = (const float*)d_in[5];
    const float* wout = (const float*)d_in[6];
    float* out = (float*)d_out;
    char* ws = (char*)d_ws;

    size_t off = 0;
    auto alloc = [&](size_t b) { size_t r = off; off += (b + 255) & ~(size_t)255; return r; };
    u16* xb     = (u16*)(ws + alloc((size_t)M_ * E_ * 2));
    u16* wqkvT  = (u16*)(ws + alloc((size_t)QKVP_ * E_ * 2));   // rows 0..3071 wq^T, 3072..3647 wkv^T, rest 0
    u16* wupT   = (u16*)(ws + alloc((size_t)NUP_ * RK_ * 2));
    u16* woutT  = (u16*)(ws + alloc((size_t)E_ * NQ_ * 2));
    u16* qb     = (u16*)(ws + alloc((size_t)B_ * H_ * L_ * DQ_ * 2));
    u16* kb     = (u16*)(ws + alloc((size_t)B_ * H_ * L_ * DQ_ * 2));
    u16* vtb    = (u16*)(ws + alloc((size_t)B_ * H_ * DQ_ * L_ * 2));
    u16* ao     = (u16*)(ws + alloc((size_t)M_ * NQ_ * 2));
    u16* ckv    = (u16*)(ws + alloc((size_t)M_ * RK_ * 2));
    u16* kropeb = (u16*)(ws + alloc((size_t)M_ * RD_ * 2));
    char* scratch = ws + alloc((size_t)M_ * NUP_ * 4);   // 83.9 MB union region
    float* qkv = (float*)(scratch);                      // M x 3840 fp32 (dead after build_q/build_ckv)
    float* up  = (float*)(scratch);                      // M x 5120 fp32 (dead after build_kvt)
    // attn partials alias scratch (qkv/up all consumed before attn):
    size_t poSz = (size_t)256 * 256 * 192 * 2;                // 25.2 MB each
    u16*   po0 = (u16*)(scratch);
    u16*   po1 = (u16*)(scratch + poSz);
    float* pm0 = (float*)(scratch + 2 * poSz);
    float* pl0 = (float*)(scratch + 2 * poSz + 256 * 256 * 4);
    float* pm1 = (float*)(scratch + 2 * poSz + 2 * 256 * 256 * 4);
    float* pl1 = (float*)(scratch + 2 * poSz + 3 * 256 * 256 * 4);

    dim3 tb(32, 8);
    int n4 = M_ * E_ / 4;
    convert_bf16<<<(n4 + 255) / 256, 256, 0, stream>>>(x, xb, n4);
    transpose_w<<<dim3(NQ_ / 32, E_ / 32), tb, 0, stream>>>(wq, wqkvT, E_, NQ_, NQ_);
    transpose_w<<<dim3((QKVP_ - NQ_) / 32, E_ / 32), tb, 0, stream>>>(wkv, wqkvT + (size_t)NQ_ * E_, E_, NKV_, QKVP_ - NQ_);
    transpose_w<<<dim3(NUP_ / 32, RK_ / 32), tb, 0, stream>>>(wup, wupT, RK_, NUP_, NUP_);
    transpose_w<<<dim3(E_ / 32, NQ_ / 32), tb, 0, stream>>>(wout, woutT, NQ_, E_, E_);

    // fused q+kv projection: 256x128 pipelined GEMM, grid 30x16 = 480 blocks (~2/CU)
    gemm256<<<dim3(QKVP_ / 128, M_ / 256), 512, 0, stream>>>(xb, wqkvT, qkv, M_, QKVP_, E_);

    int nq = M_ * H_ * 96;
    build_q<<<(nq + 255) / 256, 256, 0, stream>>>(qkv, cosT, sinT, qb);
    int nc = M_ * 288;
    build_ckv<<<(nc + 255) / 256, 256, 0, stream>>>(qkv, cosT, sinT, ckv, kropeb);

    // up-projection: keep 128^2 (N=5120 -> 1280 blocks, good occupancy)
    gemm_bt<<<dim3(NUP_ / 128, M_ / 128), 256, 0, stream>>>(ckv, wupT, up, M_, NUP_, RK_);
    build_kvt<<<B_ * H_ * 32, 256, 0, stream>>>(up, kropeb, kb, vtb);

    attn<<<256, 512, 0, stream>>>(qb, kb, vtb, po0, po1, pm0, pl0, pm1, pl1);
    attn_merge<<<(256 * 256 * 48) / 256, 256, 0, stream>>>(po0, po1, pm0, pl0, pm1, pl1, ao);

    // output projection: 256x128 GEMM, grid 16x16 = 256 blocks (full machine)
    gemm256<<<dim3(E_ / 128, M_ / 256), 512, 0, stream>>>(ao, woutT, out, M_, E_, NQ_);
}

// Round 5
// 549.332 us; speedup vs baseline: 1.1299x; 1.0646x over previous
//
#include <hip/hip_runtime.h>
#include <stdint.h>

#define H_ 16
#define DH_ 128
#define RK_ 512
#define RD_ 64
#define B_ 2
#define L_ 2048
#define E_ 2048
#define DQ_ 192            // DH+RD
#define NQ_ (H_*DQ_)       // 3072
#define NKV_ 576
#define NKVP_ 640
#define QKVP_ 3840         // fused q/kv projection width, padded to 15*256
#define NUP_ (H_*(2*DH_+RD_)) // 5120
#define M_ (B_*L_)         // 4096

typedef unsigned short u16;
typedef __bf16 bf16x8 __attribute__((ext_vector_type(8)));
typedef float floatx4 __attribute__((ext_vector_type(4)));

__device__ __forceinline__ u16 f2bf(float f) {
    union { float f; uint32_t u; } v; v.f = f;
    uint32_t u = v.u;
    u = (u + 0x7fffu + ((u >> 16) & 1u)) >> 16;
    return (u16)u;
}
__device__ __forceinline__ float bf2f(u16 b) {
    union { uint32_t u; float f; } v; v.u = ((uint32_t)b) << 16; return v.f;
}
// pack two f32 -> two bf16 (RNE), one instruction
__device__ __forceinline__ uint32_t cvtpk(float lo, float hi) {
    uint32_t r;
    asm("v_cvt_pk_bf16_f32 %0, %1, %2" : "=v"(r) : "v"(lo), "v"(hi));
    return r;
}

__device__ __forceinline__ void gld_lds16(const void* g, void* l) {
    __builtin_amdgcn_global_load_lds((__attribute__((address_space(1))) void*)(g),
                                     (__attribute__((address_space(3))) void*)(l),
                                     16, 0, 0);
}

// ---------------- fp32 -> bf16 elementwise (x) ----------------
__global__ void convert_bf16(const float* __restrict__ in, u16* __restrict__ out, int n4) {
    int i = blockIdx.x * blockDim.x + threadIdx.x;
    if (i >= n4) return;
    float4 v = ((const float4*)in)[i];
    uint2 o;
    o.x = cvtpk(v.x, v.y);
    o.y = cvtpk(v.z, v.w);
    ((uint2*)out)[i] = o;
}

// ---------------- all 4 weight transposes in ONE launch ----------------
// region table (32x32 tiles, block (32,8)):
// 0: wq   -> wqkvT            K=2048 N=3072       96x64  = 6144 blocks
// 1: wkv  -> wqkvT+3072*2048  K=2048 N=576 pad768 24x64  = 1536
// 2: wup  -> wupT             K=512  N=5120       160x16 = 2560
// 3: wout -> woutT            K=3072 N=2048       64x96  = 6144
__global__ void transpose_all(const float* __restrict__ wq, const float* __restrict__ wkv,
                              const float* __restrict__ wup, const float* __restrict__ wout,
                              u16* __restrict__ wqkvT, u16* __restrict__ wupT,
                              u16* __restrict__ woutT) {
    __shared__ float tile[32][33];
    int bid = blockIdx.x;
    const float* W; u16* Wt; int K, N, bx, by;
    if (bid < 6144)        { W = wq;   Wt = wqkvT;                      K = 2048; N = 3072; bx = bid % 96;  by = bid / 96; }
    else if (bid < 7680)   { int b = bid - 6144; W = wkv;  Wt = wqkvT + (size_t)3072 * 2048; K = 2048; N = 576;  bx = b % 24;  by = b / 24; }
    else if (bid < 10240)  { int b = bid - 7680; W = wup;  Wt = wupT;   K = 512;  N = 5120; bx = b % 160; by = b / 160; }
    else                   { int b = bid - 10240; W = wout; Wt = woutT; K = 3072; N = 2048; bx = b % 64;  by = b / 64; }
    int n0 = bx * 32, k0 = by * 32;
    int tx = threadIdx.x, ty = threadIdx.y; // 32 x 8
    for (int i = 0; i < 4; i++) {
        int k = k0 + ty + i * 8, n = n0 + tx;
        tile[ty + i * 8][tx] = (n < N) ? W[(size_t)k * N + n] : 0.f;
    }
    __syncthreads();
    for (int i = 0; i < 4; i++) {
        int n = n0 + ty + i * 8, k = k0 + tx;
        Wt[(size_t)n * K + k] = f2bf(tile[tx][ty + i * 8]);
    }
}

// ---------------- 256x128 GEMM, BK=32, TRIPLE-buffered LDS, counted vmcnt ----------------
// Pipeline (race-free by construction): tile t reads buf[t%3]; stage of tile t+2
// targets buf[(t+2)%3] == the buffer retired at end of tile t-1 (its end-barrier
// precedes the stage issue in every wave). 3 loads/thread/stage -> steady-state
// s_waitcnt vmcnt(6); never drains to 0 mid-loop (T4).
// LDS swizzle (T2): slot (row,b) holds global 16B-block b ^ ((row>>1)&3); read
// offset folds to per-lane constant qsw -> 0 bank conflicts (verified round 3).
// Requires: M % 256 == 0, N % 128 == 0, K % 32 == 0, K/32 >= 3, gridDim.y == 16.
__global__ __launch_bounds__(512, 4) void gemm256(const u16* __restrict__ A,
                                                  const u16* __restrict__ Bt,
                                                  float* __restrict__ C,
                                                  int M, int N, int K) {
    __shared__ __align__(16) u16 As[3][256 * 32];
    __shared__ __align__(16) u16 Bs[3][128 * 32];
    const int tid = threadIdx.x;
    const int wave = tid >> 6, lane = tid & 63;
    const int quad = lane >> 4, l16 = lane & 15;
    const int wm = (wave >> 1) * 64, wn = (wave & 1) * 64;

    // XCD-aware bijective swizzle (m204), bx-major: consecutive wg share B-panel
    int nwg = gridDim.x * gridDim.y;
    int flat = blockIdx.y * gridDim.x + blockIdx.x;
    int q = nwg >> 3, r = nwg & 7;
    int xcd = flat & 7, pos = flat >> 3;
    int wg = (xcd < r) ? xcd * (q + 1) + pos : r * (q + 1) + (xcd - r) * q + pos;
    const int m0 = (wg & 15) * 256;          // gridDim.y == 16 (M = 4096)
    const int n0 = (wg >> 4) * 128;

    const u16* Ab = A + (size_t)m0 * K;
    const u16* Bb = Bt + (size_t)n0 * K;

    const int qsw = (quad ^ ((l16 >> 1) & 3)) * 8;   // swizzled read offset

    floatx4 zero4 = {0.f, 0.f, 0.f, 0.f};
    floatx4 acc[4][4];
#pragma unroll
    for (int i = 0; i < 4; i++)
#pragma unroll
        for (int j = 0; j < 4; j++) acc[i][j] = zero4;

    auto stage = [&](int t, int b) {
        const u16* Ak = Ab + t * 32;
        const u16* Bk = Bb + t * 32;
#pragma unroll
        for (int it = 0; it < 2; ++it) {             // A: 256 rows x 4 blocks
            int c = it * 512 + tid;
            int row = c >> 2, blk = c & 3;
            int bg = blk ^ ((row >> 1) & 3);
            gld_lds16(Ak + (size_t)row * K + bg * 8, As[b] + row * 32 + blk * 8);
        }
        {                                             // B: 128 rows x 4 blocks
            int row = tid >> 2, blk = tid & 3;
            int bg = blk ^ ((row >> 1) & 3);
            gld_lds16(Bk + (size_t)row * K + bg * 8, Bs[b] + row * 32 + blk * 8);
        }
    };

    const int NT = K >> 5;
    stage(0, 0);
    stage(1, 1);
    int rb = 0;
    for (int t = 0; t < NT; ++t) {
        if (t + 2 < NT) {
            stage(t + 2, rb ? rb - 1 : 2);   // (rb+2)%3: buffer retired at t-1
            asm volatile("s_waitcnt vmcnt(6)" ::: "memory");   // oldest 3 (= tile t) done
        } else if (t + 1 < NT) {
            asm volatile("s_waitcnt vmcnt(3)" ::: "memory");
        } else {
            asm volatile("s_waitcnt vmcnt(0)" ::: "memory");
        }
        __builtin_amdgcn_s_barrier();        // all waves' tile-t loads landed

        const u16* Ar = As[rb];
        const u16* Br = Bs[rb];
        bf16x8 af[4], bfv[4];
#pragma unroll
        for (int i = 0; i < 4; i++) af[i]  = *(const bf16x8*)(Ar + (wm + i * 16 + l16) * 32 + qsw);
#pragma unroll
        for (int j = 0; j < 4; j++) bfv[j] = *(const bf16x8*)(Br + (wn + j * 16 + l16) * 32 + qsw);
        __builtin_amdgcn_s_setprio(1);
#pragma unroll
        for (int i = 0; i < 4; i++)
#pragma unroll
            for (int j = 0; j < 4; j++)
                acc[i][j] = __builtin_amdgcn_mfma_f32_16x16x32_bf16(af[i], bfv[j], acc[i][j], 0, 0, 0);
        __builtin_amdgcn_s_setprio(0);
        __builtin_amdgcn_s_barrier();        // buf[rb] fully read -> may be restaged
        rb = (rb == 2) ? 0 : rb + 1;
    }

#pragma unroll
    for (int i = 0; i < 4; i++)
#pragma unroll
        for (int j = 0; j < 4; j++) {
            int mrow = m0 + wm + i * 16 + quad * 4;
            int ncol = n0 + wn + j * 16 + l16;
            float* Cp = C + (size_t)mrow * N + ncol;
            for (int rr = 0; rr < 4; rr++) Cp[(size_t)rr * N] = acc[i][j][rr];
        }
}

// ---------------- fused build_q + build_ckv (one launch) ----------------
__global__ void build_qckv(const float* __restrict__ qkv, const float* __restrict__ cosT,
                           const float* __restrict__ sinT, u16* __restrict__ qb,
                           u16* __restrict__ ckv, u16* __restrict__ kropeb) {
    const float QS = 0.07216878364870323f * 1.4426950408889634f; // 1/sqrt(192) * log2(e)
    int idx = blockIdx.x * blockDim.x + threadIdx.x;
    const int NQTH = M_ * H_ * 96;
    if (idx < NQTH) {
        int p = idx % 96; int t = idx / 96; int h = t % H_; int row = t / H_;
        int l = row & (L_ - 1); int b = row >> 11;
        const float* src = qkv + (size_t)row * QKVP_ + h * DQ_;
        u16* dst = qb + ((size_t)(b * H_ + h) * L_ + l) * DQ_;
        int d = 2 * p;
        float x1 = src[d], x2 = src[d + 1];
        if (d < DH_) { dst[d] = f2bf(x1 * QS); dst[d + 1] = f2bf(x2 * QS); }
        else {
            int i = (d - DH_) >> 1;
            float c = cosT[(size_t)l * 32 + i], s = sinT[(size_t)l * 32 + i];
            dst[d]     = f2bf((x1 * c - x2 * s) * QS);
            dst[d + 1] = f2bf((x1 * s + x2 * c) * QS);
        }
    } else {
        idx -= NQTH;
        if (idx >= M_ * 288) return;
        int j = idx % 288; int row = idx / 288;
        int l = row & (L_ - 1);
        const float* src = qkv + (size_t)row * QKVP_ + NQ_;
        if (j < 256) {
            ckv[(size_t)row * RK_ + 2 * j]     = f2bf(src[2 * j]);
            ckv[(size_t)row * RK_ + 2 * j + 1] = f2bf(src[2 * j + 1]);
        } else {
            int i = j - 256;
            float x1 = src[RK_ + 2 * i], x2 = src[RK_ + 2 * i + 1];
            float c = cosT[(size_t)l * 32 + i], s = sinT[(size_t)l * 32 + i];
            kropeb[(size_t)row * RD_ + 2 * i]     = f2bf(x1 * c - x2 * s);
            kropeb[(size_t)row * RD_ + 2 * i + 1] = f2bf(x1 * s + x2 * c);
        }
    }
}

// ---------------- build k (B,H,L,192) + vT (B,H,192,L perm) bf16 ----------------
__global__ __launch_bounds__(256) void build_kvt(const float* __restrict__ up,
        const u16* __restrict__ kropeb, u16* __restrict__ kb, u16* __restrict__ vtb) {
    __shared__ float vt[64][193];
    int blk = blockIdx.x;          // (b*H+h)*32 + lt
    int lt = blk & 31; int bh = blk >> 5; int h = bh % H_; int b = bh / H_;
    int tid = threadIdx.x;
    int l0 = lt * 64;
    for (int it = 0; it < 48; ++it) {
        int idx = it * 256 + tid;  // 64*192
        int lr = idx / 192, d = idx % 192;
        size_t row = (size_t)b * L_ + l0 + lr;
        float vv = (d < DH_) ? up[row * NUP_ + h * 320 + DH_ + d]
                             : up[row * NUP_ + h * 320 + 2 * DH_ + (d - DH_)];
        vt[lr][d] = vv;
        u16 kbf = (d < DH_) ? f2bf(up[row * NUP_ + h * 320 + d])
                            : kropeb[row * RD_ + (d - DH_)];
        kb[((size_t)bh * L_ + l0 + lr) * DQ_ + d] = kbf;
    }
    __syncthreads();
    for (int it = 0; it < 48; ++it) {
        int idx = it * 256 + tid;
        int lr = idx & 63, d = idx >> 6;
        int l = l0 + lr;
        int s5 = l & 31;
        int k5 = ((s5 >> 2) & 3) * 8 + ((s5 >> 4) & 1) * 4 + (s5 & 3);
        int lp = (l & ~31) | k5;
        vtb[((size_t)bh * DQ_ + d) * L_ + lp] = f2bf(vt[lr][d]);
    }
}

// ---------------- flash attention, causal, S^T, 512-thread blocks ----------------
__global__ __launch_bounds__(512, 2) void attn(const u16* __restrict__ qb,
        const u16* __restrict__ kb, const u16* __restrict__ vtb,
        u16* __restrict__ po0, u16* __restrict__ po1,
        float* __restrict__ pm0, float* __restrict__ pl0,
        float* __restrict__ pm1, float* __restrict__ pl1) {
    __shared__ __align__(16) u16 Ks[2][64 * 192];
    __shared__ __align__(16) u16 Vs[2][192 * 64];
    int id = blockIdx.x;
    int bh = id & 31, tj = id >> 5;      // same-bh blocks share XCD (id%8 = bh%8)
    int t = tj >> 1, j = tj & 1;
    int tid = threadIdx.x, wave = tid >> 6, lane = tid & 63;
    int quad = lane >> 4, l16 = lane & 15;

    // swizzle lane constants: row&7 == l16&7 for all fragment reads
    const int x7 = l16 & 7;
    const int h2 = (x7 >> 2) & 1;
    const int qx = quad ^ (x7 & 3);
    const int oA = h2 * 32 + qx * 8;        // even kk  / V g=0
    const int oB = (1 - h2) * 32 + qx * 8;  // odd  kk  / V g=1

    u16* po = j ? po1 : po0;
    float* pm = j ? pm1 : pm0;
    float* pl = j ? pl1 : pl0;

    const u16* kbase0 = kb + (size_t)bh * L_ * DQ_;
    const u16* vbase0 = vtb + (size_t)bh * (size_t)DQ_ * L_;
    floatx4 zero4 = {0.f, 0.f, 0.f, 0.f};

    auto stageKV = [&](int st, int buf) {
        const u16* kg = kbase0 + (size_t)st * 64 * DQ_;
        u16* kd = &Ks[buf][0];
        for (int it = 0; it < 3; ++it) {
            int c = it * 512 + tid;          // 0..1535 = 64 rows * 24 blocks
            int s = c / 24, blk = c - s * 24;
            int blog = (blk & 24) | ((blk & 7) ^ (s & 7));
            gld_lds16(kg + (size_t)s * DQ_ + blog * 8, kd + c * 8);
        }
        const u16* vg = vbase0 + st * 64;
        u16* vd = &Vs[buf][0];
        for (int it = 0; it < 3; ++it) {
            int c = it * 512 + tid;          // 0..1535 = 192 rows * 8 blocks
            int d = c >> 3, blk = c & 7;
            int blog = blk ^ (d & 7);
            gld_lds16(vg + (size_t)d * L_ + blog * 8, vd + c * 8);
        }
    };

    for (int seg = 0; seg < 2; ++seg) {
        const int QT = seg == 0 ? (7 - t) : t;
        const int st0 = j ? (2 * QT + 2) : 0;
        const int st1 = j ? (4 * QT + 3) : (2 * QT + 1);

        bf16x8 aq[2][6];
        const u16* qbase = qb + ((size_t)bh * L_ + QT * 256 + wave * 16 + l16) * DQ_;
        for (int a = 0; a < 2; a++)
            for (int kk = 0; kk < 6; kk++)
                aq[a][kk] = *(const bf16x8*)(qbase + a * 128 * DQ_ + kk * 32 + quad * 8);

        floatx4 o[2][12];
        for (int a = 0; a < 2; a++) for (int i = 0; i < 12; i++) o[a][i] = zero4;
        float m_i[2] = {-INFINITY, -INFINITY};
        float l_i[2] = {0.f, 0.f};

        int cur = 0;
        stageKV(st0, 0);   // prologue: 6 loads in flight

        for (int st = st0; st <= st1; ++st) {
            if (st < st1) {
                stageKV(st + 1, cur ^ 1);                      // 6 more loads (12 in flight)
                asm volatile("s_waitcnt vmcnt(6)" ::: "memory"); // oldest 6 (= buf cur) done
            } else {
                asm volatile("s_waitcnt vmcnt(0)" ::: "memory");
            }
            __builtin_amdgcn_s_barrier();   // all waves: buf[cur] fully staged
            const u16* Kc = &Ks[cur][0];
            const u16* Vc = &Vs[cur][0];

            // liveness: R multiple of 16; rowset live iff R >= 0
            int R0 = QT * 256 + wave * 16 - st * 64;
            int R1 = R0 + 128;
            int smax0 = min(3, (R0 + 15) >> 4);
            int smax1 = min(3, (R1 + 15) >> 4);
            bool live0 = smax0 >= 0, live1 = smax1 >= 0;

            float pv[2][4][4];
            float mxa[2] = {-INFINITY, -INFINITY};
#pragma unroll
            for (int stile = 0; stile < 4; ++stile) {
                if (stile > smax1) {
                    for (int r = 0; r < 4; r++) { pv[0][stile][r] = 0.f; pv[1][stile][r] = 0.f; }
                    continue;
                }
                bool do0 = (stile <= smax0);
                floatx4 s1v = zero4, s0v = zero4;
#pragma unroll
                for (int kk = 0; kk < 6; kk++) {
                    int off = (kk >> 1) * 64 + ((kk & 1) ? oB : oA);
                    bf16x8 kf = *(const bf16x8*)(Kc + (stile * 16 + l16) * 192 + off);
                    s1v = __builtin_amdgcn_mfma_f32_16x16x32_bf16(kf, aq[1][kk], s1v, 0, 0, 0);
                    if (do0) s0v = __builtin_amdgcn_mfma_f32_16x16x32_bf16(kf, aq[0][kk], s0v, 0, 0, 0);
                }
                int sb = stile * 16;
                if (sb + 15 > R1) {
                    float v0 = (sb + quad * 4 + 0 > R1 + l16) ? -1e30f : s1v[0];
                    float v1 = (sb + quad * 4 + 1 > R1 + l16) ? -1e30f : s1v[1];
                    float v2 = (sb + quad * 4 + 2 > R1 + l16) ? -1e30f : s1v[2];
                    float v3 = (sb + quad * 4 + 3 > R1 + l16) ? -1e30f : s1v[3];
                    pv[1][stile][0] = v0; pv[1][stile][1] = v1;
                    pv[1][stile][2] = v2; pv[1][stile][3] = v3;
                    mxa[1] = fmaxf(mxa[1], fmaxf(fmaxf(v0, v1), fmaxf(v2, v3)));
                } else {
                    for (int r = 0; r < 4; r++) pv[1][stile][r] = s1v[r];
                    mxa[1] = fmaxf(mxa[1], fmaxf(fmaxf(s1v[0], s1v[1]), fmaxf(s1v[2], s1v[3])));
                }
                if (do0) {
                    if (sb + 15 > R0) {
                        float v0 = (sb + quad * 4 + 0 > R0 + l16) ? -1e30f : s0v[0];
                        float v1 = (sb + quad * 4 + 1 > R0 + l16) ? -1e30f : s0v[1];
                        float v2 = (sb + quad * 4 + 2 > R0 + l16) ? -1e30f : s0v[2];
                        float v3 = (sb + quad * 4 + 3 > R0 + l16) ? -1e30f : s0v[3];
                        pv[0][stile][0] = v0; pv[0][stile][1] = v1;
                        pv[0][stile][2] = v2; pv[0][stile][3] = v3;
                        mxa[0] = fmaxf(mxa[0], fmaxf(fmaxf(v0, v1), fmaxf(v2, v3)));
                    } else {
                        for (int r = 0; r < 4; r++) pv[0][stile][r] = s0v[r];
                        mxa[0] = fmaxf(mxa[0], fmaxf(fmaxf(s0v[0], s0v[1]), fmaxf(s0v[2], s0v[3])));
                    }
                } else {
                    for (int r = 0; r < 4; r++) pv[0][stile][r] = 0.f;
                }
            }

            // softmax reduce + (deferred) rescale, both rowsets
            bool lvA[2] = {live0, live1};
            int smxA[2] = {smax0, smax1};
            float mn_[2];
#pragma unroll
            for (int a = 0; a < 2; a++) {
                if (!lvA[a]) { mn_[a] = 0.f; continue; }
                float mx = mxa[a];
                mx = fmaxf(mx, __shfl_xor(mx, 16));
                mx = fmaxf(mx, __shfl_xor(mx, 32));
                float mn;
                if (__all(mx <= m_i[a] + 8.0f)) {
                    mn = m_i[a];                 // defer-max: keep stale max, no rescale
                } else {
                    mn = fmaxf(m_i[a], mx);
                    float alpha = exp2f(m_i[a] - mn);
                    m_i[a] = mn;
                    l_i[a] *= alpha;
                    for (int i = 0; i < 12; i++) o[a][i] *= alpha;
                }
                mn_[a] = mn;
            }

            // per-g finish: exp2 + cvt_pk pack + PV, so g=1's VALU overlaps g=0's MFMA
            float rs[2] = {0.f, 0.f};
#pragma unroll
            for (int g = 0; g < 2; g++) {
                bf16x8 pfg[2];
#pragma unroll
                for (int a = 0; a < 2; a++) {
                    uint32_t d0 = 0, d1 = 0, d2 = 0, d3 = 0;
                    if (lvA[a]) {
                        if (2 * g <= smxA[a]) {
                            float e0 = exp2f(pv[a][2 * g][0] - mn_[a]);
                            float e1 = exp2f(pv[a][2 * g][1] - mn_[a]);
                            float e2 = exp2f(pv[a][2 * g][2] - mn_[a]);
                            float e3 = exp2f(pv[a][2 * g][3] - mn_[a]);
                            rs[a] += (e0 + e1) + (e2 + e3);
                            d0 = cvtpk(e0, e1); d1 = cvtpk(e2, e3);
                        }
                        if (2 * g + 1 <= smxA[a]) {
                            float e4 = exp2f(pv[a][2 * g + 1][0] - mn_[a]);
                            float e5 = exp2f(pv[a][2 * g + 1][1] - mn_[a]);
                            float e6 = exp2f(pv[a][2 * g + 1][2] - mn_[a]);
                            float e7 = exp2f(pv[a][2 * g + 1][3] - mn_[a]);
                            rs[a] += (e4 + e5) + (e6 + e7);
                            d2 = cvtpk(e4, e5); d3 = cvtpk(e6, e7);
                        }
                    }
                    union { bf16x8 v; uint32_t d[4]; } u;
                    u.d[0] = d0; u.d[1] = d1; u.d[2] = d2; u.d[3] = d3;
                    pfg[a] = u.v;
                }
                int vo = g ? oB : oA;
#pragma unroll
                for (int dtile = 0; dtile < 12; dtile++) {
                    bf16x8 vf = *(const bf16x8*)(Vc + (dtile * 16 + l16) * 64 + vo);
                    if (live0)
                        o[0][dtile] = __builtin_amdgcn_mfma_f32_16x16x32_bf16(vf, pfg[0], o[0][dtile], 0, 0, 0);
                    if (live1)
                        o[1][dtile] = __builtin_amdgcn_mfma_f32_16x16x32_bf16(vf, pfg[1], o[1][dtile], 0, 0, 0);
                }
            }
#pragma unroll
            for (int a = 0; a < 2; a++) {
                if (!lvA[a]) continue;
                float r2 = rs[a];
                r2 += __shfl_xor(r2, 16);
                r2 += __shfl_xor(r2, 32);
                l_i[a] += r2;
            }
            __builtin_amdgcn_s_barrier();   // all waves done reading buf[cur] -> reusable
            cur ^= 1;
        }

        // write partials: po[tile][q 256][d 192] bf16, pm/pl[tile][q 256]
        int tile = bh * 8 + QT;
        for (int a = 0; a < 2; a++) {
            int q = a * 128 + wave * 16 + l16;
            u16* dst = po + ((size_t)tile * 256 + q) * 192;
            for (int dtile = 0; dtile < 12; dtile++) {
                uint2 pk2;
                pk2.x = cvtpk(o[a][dtile][0], o[a][dtile][1]);
                pk2.y = cvtpk(o[a][dtile][2], o[a][dtile][3]);
                *(uint2*)(dst + dtile * 16 + quad * 4) = pk2;
            }
            if (quad == 0) {
                pm[(size_t)tile * 256 + q] = m_i[a];
                pl[(size_t)tile * 256 + q] = l_i[a];
            }
        }
        __syncthreads();
    }
}

// ---------------- merge the two split-s halves -> ao (B,L,H,192) bf16 ----------------
__global__ void attn_merge(const u16* __restrict__ po0, const u16* __restrict__ po1,
                           const float* __restrict__ pm0, const float* __restrict__ pl0,
                           const float* __restrict__ pm1, const float* __restrict__ pl1,
                           u16* __restrict__ ao) {
    int idx = blockIdx.x * blockDim.x + threadIdx.x;   // 256*256*48
    int c = idx % 48; int rest = idx / 48;
    int q = rest & 255; int tile = rest >> 8;
    int bh = tile >> 3, QT = tile & 7;
    size_t mi = (size_t)tile * 256 + q;
    float m0 = pm0[mi], m1 = pm1[mi];
    float l0 = pl0[mi], l1 = pl1[mi];
    float m = fmaxf(m0, m1);
    float a0 = exp2f(m0 - m), a1 = exp2f(m1 - m);
    float inv = 1.0f / (l0 * a0 + l1 * a1);
    float s0 = a0 * inv, s1 = a1 * inv;
    ushort4 u0 = *(const ushort4*)(po0 + mi * 192 + c * 4);
    ushort4 u1 = *(const ushort4*)(po1 + mi * 192 + c * 4);
    int b = bh >> 4, h = bh & 15;
    int l = QT * 256 + q;
    u16* dst = ao + (((size_t)(b * L_ + l)) * H_ + h) * DQ_ + c * 4;
    uint2 pk2;
    pk2.x = cvtpk(bf2f(u0.x) * s0 + bf2f(u1.x) * s1, bf2f(u0.y) * s0 + bf2f(u1.y) * s1);
    pk2.y = cvtpk(bf2f(u0.z) * s0 + bf2f(u1.z) * s1, bf2f(u0.w) * s0 + bf2f(u1.w) * s1);
    *(uint2*)dst = pk2;
}

extern "C" void kernel_launch(void* const* d_in, const int* in_sizes, int n_in,
                              void* d_out, int out_size, void* d_ws, size_t ws_size,
                              hipStream_t stream) {
    const float* x    = (const float*)d_in[0];
    const float* cosT = (const float*)d_in[1];
    const float* sinT = (const float*)d_in[2];
    const float* wq   = (const float*)d_in[3];
    const float* wkv  = (const float*)d_in[4];
    const float* wup  = (const float*)d_in[5];
    const float* wout = (const float*)d_in[6];
    float* out = (float*)d_out;
    char* ws = (char*)d_ws;

    size_t off = 0;
    auto alloc = [&](size_t b) { size_t r = off; off += (b + 255) & ~(size_t)255; return r; };
    u16* xb     = (u16*)(ws + alloc((size_t)M_ * E_ * 2));
    u16* wqkvT  = (u16*)(ws + alloc((size_t)QKVP_ * E_ * 2));   // rows 0..3071 wq^T, 3072..3647 wkv^T, rest 0
    u16* wupT   = (u16*)(ws + alloc((size_t)NUP_ * RK_ * 2));
    u16* woutT  = (u16*)(ws + alloc((size_t)E_ * NQ_ * 2));
    u16* qb     = (u16*)(ws + alloc((size_t)B_ * H_ * L_ * DQ_ * 2));
    u16* kb     = (u16*)(ws + alloc((size_t)B_ * H_ * L_ * DQ_ * 2));
    u16* vtb    = (u16*)(ws + alloc((size_t)B_ * H_ * DQ_ * L_ * 2));
    u16* ao     = (u16*)(ws + alloc((size_t)M_ * NQ_ * 2));
    u16* ckv    = (u16*)(ws + alloc((size_t)M_ * RK_ * 2));
    u16* kropeb = (u16*)(ws + alloc((size_t)M_ * RD_ * 2));
    char* scratch = ws + alloc((size_t)M_ * NUP_ * 4);   // 83.9 MB union region
    float* qkv = (float*)(scratch);                      // M x 3840 fp32 (dead after build_qckv)
    float* up  = (float*)(scratch);                      // M x 5120 fp32 (dead after build_kvt)
    // attn partials alias scratch (qkv/up all consumed before attn):
    size_t poSz = (size_t)256 * 256 * 192 * 2;                // 25.2 MB each
    u16*   po0 = (u16*)(scratch);
    u16*   po1 = (u16*)(scratch + poSz);
    float* pm0 = (float*)(scratch + 2 * poSz);
    float* pl0 = (float*)(scratch + 2 * poSz + 256 * 256 * 4);
    float* pm1 = (float*)(scratch + 2 * poSz + 2 * 256 * 256 * 4);
    float* pl1 = (float*)(scratch + 2 * poSz + 3 * 256 * 256 * 4);

    dim3 tb(32, 8);
    int n4 = M_ * E_ / 4;
    convert_bf16<<<(n4 + 255) / 256, 256, 0, stream>>>(x, xb, n4);
    transpose_all<<<16384, tb, 0, stream>>>(wq, wkv, wup, wout, wqkvT, wupT, woutT);

    // fused q+kv projection: 256x128 pipelined GEMM, grid 30x16 = 480 blocks
    gemm256<<<dim3(QKVP_ / 128, M_ / 256), 512, 0, stream>>>(xb, wqkvT, qkv, M_, QKVP_, E_);

    int nb = (M_ * H_ * 96 + M_ * 288) / 256;
    build_qckv<<<nb, 256, 0, stream>>>(qkv, cosT, sinT, qb, ckv, kropeb);

    // up-projection: 256x128 pipelined GEMM, grid 40x16 = 640 blocks (K=512, NT=16)
    gemm256<<<dim3(NUP_ / 128, M_ / 256), 512, 0, stream>>>(ckv, wupT, up, M_, NUP_, RK_);
    build_kvt<<<B_ * H_ * 32, 256, 0, stream>>>(up, kropeb, kb, vtb);

    attn<<<256, 512, 0, stream>>>(qb, kb, vtb, po0, po1, pm0, pl0, pm1, pl1);
    attn_merge<<<(256 * 256 * 48) / 256, 256, 0, stream>>>(po0, po1, pm0, pl0, pm1, pl1, ao);

    // output projection: 256x128 GEMM, grid 16x16 = 256 blocks (full machine)
    gemm256<<<dim3(E_ / 128, M_ / 256), 512, 0, stream>>>(ao, woutT, out, M_, E_, NQ_);
}

// Round 6
// 494.449 us; speedup vs baseline: 1.2554x; 1.1110x over previous
//
#include <hip/hip_runtime.h>
#include <stdint.h>

#define H_ 16
#define DH_ 128
#define RK_ 512
#define RD_ 64
#define B_ 2
#define L_ 2048
#define E_ 2048
#define DQ_ 192            // DH+RD
#define NQ_ (H_*DQ_)       // 3072
#define NKV_ 576
#define QKVP_ 3840         // fused q/kv projection width, padded to 15*256
#define NUP_ (H_*(2*DH_+RD_)) // 5120
#define M_ (B_*L_)         // 4096

typedef unsigned short u16;
typedef __bf16 bf16x8 __attribute__((ext_vector_type(8)));
typedef float floatx4 __attribute__((ext_vector_type(4)));

__device__ __forceinline__ u16 f2bf(float f) {
    union { float f; uint32_t u; } v; v.f = f;
    uint32_t u = v.u;
    u = (u + 0x7fffu + ((u >> 16) & 1u)) >> 16;
    return (u16)u;
}
__device__ __forceinline__ float bf2f(u16 b) {
    union { uint32_t u; float f; } v; v.u = ((uint32_t)b) << 16; return v.f;
}
// pack two f32 -> two bf16 (RNE), one instruction
__device__ __forceinline__ uint32_t cvtpk(float lo, float hi) {
    uint32_t r;
    asm("v_cvt_pk_bf16_f32 %0, %1, %2" : "=v"(r) : "v"(lo), "v"(hi));
    return r;
}

__device__ __forceinline__ void gld_lds16(const void* g, void* l) {
    __builtin_amdgcn_global_load_lds((__attribute__((address_space(1))) void*)(g),
                                     (__attribute__((address_space(3))) void*)(l),
                                     16, 0, 0);
}

// ---------------- fp32 -> bf16 elementwise (x) ----------------
__global__ void convert_bf16(const float* __restrict__ in, u16* __restrict__ out, int n4) {
    int i = blockIdx.x * blockDim.x + threadIdx.x;
    if (i >= n4) return;
    float4 v = ((const float4*)in)[i];
    uint2 o;
    o.x = cvtpk(v.x, v.y);
    o.y = cvtpk(v.z, v.w);
    ((uint2*)out)[i] = o;
}

// ---------------- all 4 weight transposes in ONE launch ----------------
__global__ void transpose_all(const float* __restrict__ wq, const float* __restrict__ wkv,
                              const float* __restrict__ wup, const float* __restrict__ wout,
                              u16* __restrict__ wqkvT, u16* __restrict__ wupT,
                              u16* __restrict__ woutT) {
    __shared__ float tile[32][33];
    int bid = blockIdx.x;
    const float* W; u16* Wt; int K, N, bx, by;
    if (bid < 6144)        { W = wq;   Wt = wqkvT;                      K = 2048; N = 3072; bx = bid % 96;  by = bid / 96; }
    else if (bid < 7680)   { int b = bid - 6144; W = wkv;  Wt = wqkvT + (size_t)3072 * 2048; K = 2048; N = 576;  bx = b % 24;  by = b / 24; }
    else if (bid < 10240)  { int b = bid - 7680; W = wup;  Wt = wupT;   K = 512;  N = 5120; bx = b % 160; by = b / 160; }
    else                   { int b = bid - 10240; W = wout; Wt = woutT; K = 3072; N = 2048; bx = b % 64;  by = b / 64; }
    int n0 = bx * 32, k0 = by * 32;
    int tx = threadIdx.x, ty = threadIdx.y; // 32 x 8
    for (int i = 0; i < 4; i++) {
        int k = k0 + ty + i * 8, n = n0 + tx;
        tile[ty + i * 8][tx] = (n < N) ? W[(size_t)k * N + n] : 0.f;
    }
    __syncthreads();
    for (int i = 0; i < 4; i++) {
        int n = n0 + ty + i * 8, k = k0 + tx;
        Wt[(size_t)n * K + k] = f2bf(tile[tx][ty + i * 8]);
    }
}

// ---------------- 256x128 GEMM, BK=32, TRIPLE-buffered LDS, counted vmcnt ----------------
// Pipeline (race-free by construction): tile t reads buf[t%3]; stage of tile t+2
// targets buf[(t+2)%3] == the buffer retired at end of tile t-1. 3 loads/thread/
// stage -> steady-state s_waitcnt vmcnt(6); never drains to 0 mid-loop (T4).
// LDS swizzle (T2): 0 bank conflicts (verified round 3). lda = A row stride
// (lets A be a column-slice of a wider buffer). BF16OUT: emit bf16 C directly
// (all consumers convert anyway -> halves intermediate HBM traffic).
// Requires: M % 256 == 0, N % 128 == 0, K % 32 == 0, K/32 >= 3, gridDim.y == 16.
template<bool BF16OUT>
__global__ __launch_bounds__(512, 4) void gemm256(const u16* __restrict__ A,
                                                  const u16* __restrict__ Bt,
                                                  void* __restrict__ Cv,
                                                  int M, int N, int K, int lda) {
    __shared__ __align__(16) u16 As[3][256 * 32];
    __shared__ __align__(16) u16 Bs[3][128 * 32];
    const int tid = threadIdx.x;
    const int wave = tid >> 6, lane = tid & 63;
    const int quad = lane >> 4, l16 = lane & 15;
    const int wm = (wave >> 1) * 64, wn = (wave & 1) * 64;

    // XCD-aware bijective swizzle (m204), bx-major: consecutive wg share B-panel
    int nwg = gridDim.x * gridDim.y;
    int flat = blockIdx.y * gridDim.x + blockIdx.x;
    int q = nwg >> 3, r = nwg & 7;
    int xcd = flat & 7, pos = flat >> 3;
    int wg = (xcd < r) ? xcd * (q + 1) + pos : r * (q + 1) + (xcd - r) * q + pos;
    const int m0 = (wg & 15) * 256;          // gridDim.y == 16 (M = 4096)
    const int n0 = (wg >> 4) * 128;

    const u16* Ab = A + (size_t)m0 * lda;
    const u16* Bb = Bt + (size_t)n0 * K;

    const int qsw = (quad ^ ((l16 >> 1) & 3)) * 8;   // swizzled read offset

    floatx4 zero4 = {0.f, 0.f, 0.f, 0.f};
    floatx4 acc[4][4];
#pragma unroll
    for (int i = 0; i < 4; i++)
#pragma unroll
        for (int j = 0; j < 4; j++) acc[i][j] = zero4;

    auto stage = [&](int t, int b) {
        const u16* Ak = Ab + t * 32;
        const u16* Bk = Bb + t * 32;
#pragma unroll
        for (int it = 0; it < 2; ++it) {             // A: 256 rows x 4 blocks
            int c = it * 512 + tid;
            int row = c >> 2, blk = c & 3;
            int bg = blk ^ ((row >> 1) & 3);
            gld_lds16(Ak + (size_t)row * lda + bg * 8, As[b] + row * 32 + blk * 8);
        }
        {                                             // B: 128 rows x 4 blocks
            int row = tid >> 2, blk = tid & 3;
            int bg = blk ^ ((row >> 1) & 3);
            gld_lds16(Bk + (size_t)row * K + bg * 8, Bs[b] + row * 32 + blk * 8);
        }
    };

    const int NT = K >> 5;
    stage(0, 0);
    stage(1, 1);
    int rb = 0;
    for (int t = 0; t < NT; ++t) {
        if (t + 2 < NT) {
            stage(t + 2, rb ? rb - 1 : 2);   // (rb+2)%3: buffer retired at t-1
            asm volatile("s_waitcnt vmcnt(6)" ::: "memory");   // oldest 3 (= tile t) done
        } else if (t + 1 < NT) {
            asm volatile("s_waitcnt vmcnt(3)" ::: "memory");
        } else {
            asm volatile("s_waitcnt vmcnt(0)" ::: "memory");
        }
        __builtin_amdgcn_s_barrier();        // all waves' tile-t loads landed

        const u16* Ar = As[rb];
        const u16* Br = Bs[rb];
        bf16x8 af[4], bfv[4];
#pragma unroll
        for (int i = 0; i < 4; i++) af[i]  = *(const bf16x8*)(Ar + (wm + i * 16 + l16) * 32 + qsw);
#pragma unroll
        for (int j = 0; j < 4; j++) bfv[j] = *(const bf16x8*)(Br + (wn + j * 16 + l16) * 32 + qsw);
        __builtin_amdgcn_s_setprio(1);
#pragma unroll
        for (int i = 0; i < 4; i++)
#pragma unroll
            for (int j = 0; j < 4; j++)
                acc[i][j] = __builtin_amdgcn_mfma_f32_16x16x32_bf16(af[i], bfv[j], acc[i][j], 0, 0, 0);
        __builtin_amdgcn_s_setprio(0);
        __builtin_amdgcn_s_barrier();        // buf[rb] fully read -> may be restaged
        rb = (rb == 2) ? 0 : rb + 1;
    }

#pragma unroll
    for (int i = 0; i < 4; i++)
#pragma unroll
        for (int j = 0; j < 4; j++) {
            int mrow = m0 + wm + i * 16 + quad * 4;
            int ncol = n0 + wn + j * 16 + l16;
            if (BF16OUT) {
                u16* Cp = (u16*)Cv + (size_t)mrow * N + ncol;
                for (int rr = 0; rr < 4; rr++) Cp[(size_t)rr * N] = f2bf(acc[i][j][rr]);
            } else {
                float* Cp = (float*)Cv + (size_t)mrow * N + ncol;
                for (int rr = 0; rr < 4; rr++) Cp[(size_t)rr * N] = acc[i][j][rr];
            }
        }
}

// ---------------- fused build_q + k_rope from bf16 qkv ----------------
// q part: rope + scale -> qb (B,H,L,192). rope part: roped k_rope -> kropeb.
// (c_kv needs no copy: up-GEMM reads qkv cols 3072..3583 directly via lda.)
__global__ void build_qckv(const u16* __restrict__ qkv, const float* __restrict__ cosT,
                           const float* __restrict__ sinT, u16* __restrict__ qb,
                           u16* __restrict__ kropeb) {
    const float QS = 0.07216878364870323f * 1.4426950408889634f; // 1/sqrt(192) * log2(e)
    int idx = blockIdx.x * blockDim.x + threadIdx.x;
    const int NQTH = M_ * H_ * 96;
    if (idx < NQTH) {
        int p = idx % 96; int t = idx / 96; int h = t % H_; int row = t / H_;
        int l = row & (L_ - 1); int b = row >> 11;
        const u16* src = qkv + (size_t)row * QKVP_ + h * DQ_;
        u16* dst = qb + ((size_t)(b * H_ + h) * L_ + l) * DQ_;
        int d = 2 * p;
        uint32_t w = *(const uint32_t*)(src + d);
        float x1 = bf2f((u16)(w & 0xffff)), x2 = bf2f((u16)(w >> 16));
        uint32_t o;
        if (d < DH_) o = cvtpk(x1 * QS, x2 * QS);
        else {
            int i = (d - DH_) >> 1;
            float c = cosT[(size_t)l * 32 + i], s = sinT[(size_t)l * 32 + i];
            o = cvtpk((x1 * c - x2 * s) * QS, (x1 * s + x2 * c) * QS);
        }
        *(uint32_t*)(dst + d) = o;
    } else {
        idx -= NQTH;
        if (idx >= M_ * 32) return;
        int i = idx & 31; int row = idx >> 5;
        int l = row & (L_ - 1);
        uint32_t w = *(const uint32_t*)(qkv + (size_t)row * QKVP_ + NQ_ + RK_ + 2 * i);
        float x1 = bf2f((u16)(w & 0xffff)), x2 = bf2f((u16)(w >> 16));
        float c = cosT[(size_t)l * 32 + i], s = sinT[(size_t)l * 32 + i];
        *(uint32_t*)(kropeb + (size_t)row * RD_ + 2 * i) = cvtpk(x1 * c - x2 * s, x1 * s + x2 * c);
    }
}

// ---------------- build k (B,H,L,192) + vT (B,H,192,L perm) from bf16 up ----------------
__global__ __launch_bounds__(256) void build_kvt(const u16* __restrict__ up,
        const u16* __restrict__ kropeb, u16* __restrict__ kb, u16* __restrict__ vtb) {
    __shared__ u16 vt[64][193];
    int blk = blockIdx.x;          // (b*H+h)*32 + lt
    int lt = blk & 31; int bh = blk >> 5; int h = bh % H_; int b = bh / H_;
    int tid = threadIdx.x;
    int l0 = lt * 64;
    for (int it = 0; it < 48; ++it) {
        int idx = it * 256 + tid;  // 64*192
        int lr = idx / 192, d = idx % 192;
        size_t row = (size_t)b * L_ + l0 + lr;
        u16 vv = (d < DH_) ? up[row * NUP_ + h * 320 + DH_ + d]
                           : up[row * NUP_ + h * 320 + 2 * DH_ + (d - DH_)];
        vt[lr][d] = vv;
        u16 kbf = (d < DH_) ? up[row * NUP_ + h * 320 + d]
                            : kropeb[row * RD_ + (d - DH_)];
        kb[((size_t)bh * L_ + l0 + lr) * DQ_ + d] = kbf;
    }
    __syncthreads();
    for (int it = 0; it < 48; ++it) {
        int idx = it * 256 + tid;
        int lr = idx & 63, d = idx >> 6;
        int l = l0 + lr;
        int s5 = l & 31;
        int k5 = ((s5 >> 2) & 3) * 8 + ((s5 >> 4) & 1) * 4 + (s5 & 3);
        int lp = (l & ~31) | k5;
        vtb[((size_t)bh * DQ_ + d) * L_ + lp] = vt[lr][d];
    }
}

// ---------------- flash attention, causal, S^T, 512-thread blocks ----------------
// (inner loop reverted to the round-3 structure measured at 126.4 us)
__global__ __launch_bounds__(512, 2) void attn(const u16* __restrict__ qb,
        const u16* __restrict__ kb, const u16* __restrict__ vtb,
        u16* __restrict__ po0, u16* __restrict__ po1,
        float* __restrict__ pm0, float* __restrict__ pl0,
        float* __restrict__ pm1, float* __restrict__ pl1) {
    __shared__ __align__(16) u16 Ks[2][64 * 192];
    __shared__ __align__(16) u16 Vs[2][192 * 64];
    int id = blockIdx.x;
    int bh = id & 31, tj = id >> 5;      // same-bh blocks share XCD (id%8 = bh%8)
    int t = tj >> 1, j = tj & 1;
    int tid = threadIdx.x, wave = tid >> 6, lane = tid & 63;
    int quad = lane >> 4, l16 = lane & 15;

    // swizzle lane constants: row&7 == l16&7 for all fragment reads
    const int x7 = l16 & 7;
    const int h2 = (x7 >> 2) & 1;
    const int qx = quad ^ (x7 & 3);
    const int oA = h2 * 32 + qx * 8;        // even kk  / V g=0
    const int oB = (1 - h2) * 32 + qx * 8;  // odd  kk  / V g=1

    u16* po = j ? po1 : po0;
    float* pm = j ? pm1 : pm0;
    float* pl = j ? pl1 : pl0;

    const u16* kbase0 = kb + (size_t)bh * L_ * DQ_;
    const u16* vbase0 = vtb + (size_t)bh * (size_t)DQ_ * L_;
    floatx4 zero4 = {0.f, 0.f, 0.f, 0.f};

    auto stageKV = [&](int st, int buf) {
        const u16* kg = kbase0 + (size_t)st * 64 * DQ_;
        u16* kd = &Ks[buf][0];
        for (int it = 0; it < 3; ++it) {
            int c = it * 512 + tid;          // 0..1535 = 64 rows * 24 blocks
            int s = c / 24, blk = c - s * 24;
            int blog = (blk & 24) | ((blk & 7) ^ (s & 7));
            gld_lds16(kg + (size_t)s * DQ_ + blog * 8, kd + c * 8);
        }
        const u16* vg = vbase0 + st * 64;
        u16* vd = &Vs[buf][0];
        for (int it = 0; it < 3; ++it) {
            int c = it * 512 + tid;          // 0..1535 = 192 rows * 8 blocks
            int d = c >> 3, blk = c & 7;
            int blog = blk ^ (d & 7);
            gld_lds16(vg + (size_t)d * L_ + blog * 8, vd + c * 8);
        }
    };

    for (int seg = 0; seg < 2; ++seg) {
        const int QT = seg == 0 ? (7 - t) : t;
        const int st0 = j ? (2 * QT + 2) : 0;
        const int st1 = j ? (4 * QT + 3) : (2 * QT + 1);

        bf16x8 aq[2][6];
        const u16* qbase = qb + ((size_t)bh * L_ + QT * 256 + wave * 16 + l16) * DQ_;
        for (int a = 0; a < 2; a++)
            for (int kk = 0; kk < 6; kk++)
                aq[a][kk] = *(const bf16x8*)(qbase + a * 128 * DQ_ + kk * 32 + quad * 8);

        floatx4 o[2][12];
        for (int a = 0; a < 2; a++) for (int i = 0; i < 12; i++) o[a][i] = zero4;
        float m_i[2] = {-INFINITY, -INFINITY};
        float l_i[2] = {0.f, 0.f};

        int cur = 0;
        stageKV(st0, 0);   // prologue: 6 loads in flight

        for (int st = st0; st <= st1; ++st) {
            if (st < st1) {
                stageKV(st + 1, cur ^ 1);                      // 6 more loads (12 in flight)
                asm volatile("s_waitcnt vmcnt(6)" ::: "memory"); // oldest 6 (= buf cur) done
            } else {
                asm volatile("s_waitcnt vmcnt(0)" ::: "memory");
            }
            __builtin_amdgcn_s_barrier();   // all waves: buf[cur] fully staged
            const u16* Kc = &Ks[cur][0];
            const u16* Vc = &Vs[cur][0];

            // liveness: R multiple of 16; rowset live iff R >= 0
            int R0 = QT * 256 + wave * 16 - st * 64;
            int R1 = R0 + 128;
            int smax0 = min(3, (R0 + 15) >> 4);
            int smax1 = min(3, (R1 + 15) >> 4);
            bool live0 = smax0 >= 0, live1 = smax1 >= 0;

            float pv[2][4][4];
            float mxa[2] = {-INFINITY, -INFINITY};
#pragma unroll
            for (int stile = 0; stile < 4; ++stile) {
                if (stile > smax1) {
                    for (int r = 0; r < 4; r++) { pv[0][stile][r] = 0.f; pv[1][stile][r] = 0.f; }
                    continue;
                }
                bool do0 = (stile <= smax0);
                floatx4 s1v = zero4, s0v = zero4;
#pragma unroll
                for (int kk = 0; kk < 6; kk++) {
                    int off = (kk >> 1) * 64 + ((kk & 1) ? oB : oA);
                    bf16x8 kf = *(const bf16x8*)(Kc + (stile * 16 + l16) * 192 + off);
                    s1v = __builtin_amdgcn_mfma_f32_16x16x32_bf16(kf, aq[1][kk], s1v, 0, 0, 0);
                    if (do0) s0v = __builtin_amdgcn_mfma_f32_16x16x32_bf16(kf, aq[0][kk], s0v, 0, 0, 0);
                }
                int sb = stile * 16;
                if (sb + 15 > R1) {
                    for (int r = 0; r < 4; r++) {
                        float v = (sb + quad * 4 + r > R1 + l16) ? -1e30f : s1v[r];
                        pv[1][stile][r] = v; mxa[1] = fmaxf(mxa[1], v);
                    }
                } else {
                    for (int r = 0; r < 4; r++) { pv[1][stile][r] = s1v[r]; mxa[1] = fmaxf(mxa[1], s1v[r]); }
                }
                if (do0) {
                    if (sb + 15 > R0) {
                        for (int r = 0; r < 4; r++) {
                            float v = (sb + quad * 4 + r > R0 + l16) ? -1e30f : s0v[r];
                            pv[0][stile][r] = v; mxa[0] = fmaxf(mxa[0], v);
                        }
                    } else {
                        for (int r = 0; r < 4; r++) { pv[0][stile][r] = s0v[r]; mxa[0] = fmaxf(mxa[0], s0v[r]); }
                    }
                } else {
                    for (int r = 0; r < 4; r++) pv[0][stile][r] = 0.f;
                }
            }

            bf16x8 pf[2][2];
            bool lv[2] = {live0, live1};
            int smx[2] = {smax0, smax1};
#pragma unroll
            for (int a = 0; a < 2; a++) {
                if (!lv[a]) continue;
                float mx = mxa[a];
                mx = fmaxf(mx, __shfl_xor(mx, 16));
                mx = fmaxf(mx, __shfl_xor(mx, 32));
                float mn;
                if (__all(mx <= m_i[a] + 8.0f)) {
                    mn = m_i[a];                 // defer-max: keep stale max, no rescale
                } else {
                    mn = fmaxf(m_i[a], mx);
                    float alpha = exp2f(m_i[a] - mn);
                    m_i[a] = mn;
                    l_i[a] *= alpha;
                    for (int i = 0; i < 12; i++) o[a][i] *= alpha;
                }
                float rs = 0.f;
#pragma unroll
                for (int stile = 0; stile < 4; ++stile) {
                    if (stile > smx[a]) continue;
                    for (int r = 0; r < 4; r++) {
                        float e = exp2f(pv[a][stile][r] - mn);
                        pv[a][stile][r] = e;
                        rs += e;
                    }
                }
                rs += __shfl_xor(rs, 16);
                rs += __shfl_xor(rs, 32);
                l_i[a] += rs;
                for (int g = 0; g < 2; g++) {
                    union { bf16x8 v; u16 s[8]; } u;
                    for (int r = 0; r < 4; r++) {
                        u.s[r]     = f2bf(pv[a][g * 2][r]);
                        u.s[4 + r] = f2bf(pv[a][g * 2 + 1][r]);
                    }
                    pf[a][g] = u.v;
                }
            }

            for (int g = 0; g < 2; g++) {
                int vo = g ? oB : oA;
#pragma unroll
                for (int dtile = 0; dtile < 12; dtile++) {
                    bf16x8 vf = *(const bf16x8*)(Vc + (dtile * 16 + l16) * 64 + vo);
                    if (live0)
                        o[0][dtile] = __builtin_amdgcn_mfma_f32_16x16x32_bf16(vf, pf[0][g], o[0][dtile], 0, 0, 0);
                    if (live1)
                        o[1][dtile] = __builtin_amdgcn_mfma_f32_16x16x32_bf16(vf, pf[1][g], o[1][dtile], 0, 0, 0);
                }
            }
            __builtin_amdgcn_s_barrier();   // all waves done reading buf[cur] -> reusable
            cur ^= 1;
        }

        // write partials: po[tile][q 256][d 192] bf16, pm/pl[tile][q 256]
        int tile = bh * 8 + QT;
        for (int a = 0; a < 2; a++) {
            int q = a * 128 + wave * 16 + l16;
            u16* dst = po + ((size_t)tile * 256 + q) * 192;
            for (int dtile = 0; dtile < 12; dtile++) {
                ushort4 pk;
                pk.x = f2bf(o[a][dtile][0]);
                pk.y = f2bf(o[a][dtile][1]);
                pk.z = f2bf(o[a][dtile][2]);
                pk.w = f2bf(o[a][dtile][3]);
                *(ushort4*)(dst + dtile * 16 + quad * 4) = pk;
            }
            if (quad == 0) {
                pm[(size_t)tile * 256 + q] = m_i[a];
                pl[(size_t)tile * 256 + q] = l_i[a];
            }
        }
        __syncthreads();
    }
}

// ---------------- merge the two split-s halves -> ao (B,L,H,192) bf16 ----------------
__global__ void attn_merge(const u16* __restrict__ po0, const u16* __restrict__ po1,
                           const float* __restrict__ pm0, const float* __restrict__ pl0,
                           const float* __restrict__ pm1, const float* __restrict__ pl1,
                           u16* __restrict__ ao) {
    int idx = blockIdx.x * blockDim.x + threadIdx.x;   // 256*256*48
    int c = idx % 48; int rest = idx / 48;
    int q = rest & 255; int tile = rest >> 8;
    int bh = tile >> 3, QT = tile & 7;
    size_t mi = (size_t)tile * 256 + q;
    float m0 = pm0[mi], m1 = pm1[mi];
    float l0 = pl0[mi], l1 = pl1[mi];
    float m = fmaxf(m0, m1);
    float a0 = exp2f(m0 - m), a1 = exp2f(m1 - m);
    float inv = 1.0f / (l0 * a0 + l1 * a1);
    float s0 = a0 * inv, s1 = a1 * inv;
    ushort4 u0 = *(const ushort4*)(po0 + mi * 192 + c * 4);
    ushort4 u1 = *(const ushort4*)(po1 + mi * 192 + c * 4);
    int b = bh >> 4, h = bh & 15;
    int l = QT * 256 + q;
    u16* dst = ao + (((size_t)(b * L_ + l)) * H_ + h) * DQ_ + c * 4;
    uint2 pk2;
    pk2.x = cvtpk(bf2f(u0.x) * s0 + bf2f(u1.x) * s1, bf2f(u0.y) * s0 + bf2f(u1.y) * s1);
    pk2.y = cvtpk(bf2f(u0.z) * s0 + bf2f(u1.z) * s1, bf2f(u0.w) * s0 + bf2f(u1.w) * s1);
    *(uint2*)dst = pk2;
}

extern "C" void kernel_launch(void* const* d_in, const int* in_sizes, int n_in,
                              void* d_out, int out_size, void* d_ws, size_t ws_size,
                              hipStream_t stream) {
    const float* x    = (const float*)d_in[0];
    const float* cosT = (const float*)d_in[1];
    const float* sinT = (const float*)d_in[2];
    const float* wq   = (const float*)d_in[3];
    const float* wkv  = (const float*)d_in[4];
    const float* wup  = (const float*)d_in[5];
    const float* wout = (const float*)d_in[6];
    float* out = (float*)d_out;
    char* ws = (char*)d_ws;

    size_t off = 0;
    auto alloc = [&](size_t b) { size_t r = off; off += (b + 255) & ~(size_t)255; return r; };
    u16* xb     = (u16*)(ws + alloc((size_t)M_ * E_ * 2));
    u16* wqkvT  = (u16*)(ws + alloc((size_t)QKVP_ * E_ * 2));   // rows 0..3071 wq^T, 3072..3647 wkv^T, rest 0
    u16* wupT   = (u16*)(ws + alloc((size_t)NUP_ * RK_ * 2));
    u16* woutT  = (u16*)(ws + alloc((size_t)E_ * NQ_ * 2));
    u16* qb     = (u16*)(ws + alloc((size_t)B_ * H_ * L_ * DQ_ * 2));
    u16* kb     = (u16*)(ws + alloc((size_t)B_ * H_ * L_ * DQ_ * 2));
    u16* vtb    = (u16*)(ws + alloc((size_t)B_ * H_ * DQ_ * L_ * 2));
    u16* ao     = (u16*)(ws + alloc((size_t)M_ * NQ_ * 2));
    u16* kropeb = (u16*)(ws + alloc((size_t)M_ * RD_ * 2));
    char* scratch = ws + alloc((size_t)M_ * NUP_ * 4);   // 83.9 MB union region
    // bf16 intermediates: qkvb [M x 3840] at scratch+0, upb [M x 5120] AFTER it
    // (up-GEMM reads qkvb cols 3072.. while writing upb -> must not alias!)
    u16* qkvb = (u16*)(scratch);                                  // 31.5 MB
    size_t qkvSz = ((size_t)M_ * QKVP_ * 2 + 255) & ~(size_t)255;
    u16* upb  = (u16*)(scratch + qkvSz);                          // 41.9 MB (total 73.4 < 83.9)
    // attn partials alias scratch (qkvb/upb consumed before attn):
    size_t poSz = (size_t)256 * 256 * 192 * 2;                    // 25.2 MB each
    u16*   po0 = (u16*)(scratch);
    u16*   po1 = (u16*)(scratch + poSz);
    float* pm0 = (float*)(scratch + 2 * poSz);
    float* pl0 = (float*)(scratch + 2 * poSz + 256 * 256 * 4);
    float* pm1 = (float*)(scratch + 2 * poSz + 2 * 256 * 256 * 4);
    float* pl1 = (float*)(scratch + 2 * poSz + 3 * 256 * 256 * 4);

    dim3 tb(32, 8);
    int n4 = M_ * E_ / 4;
    convert_bf16<<<(n4 + 255) / 256, 256, 0, stream>>>(x, xb, n4);
    transpose_all<<<16384, tb, 0, stream>>>(wq, wkv, wup, wout, wqkvT, wupT, woutT);

    // fused q+kv projection: 256x128 GEMM, bf16 out, grid 30x16 = 480 blocks
    gemm256<true><<<dim3(QKVP_ / 128, M_ / 256), 512, 0, stream>>>(xb, wqkvT, qkvb, M_, QKVP_, E_, E_);

    int nb = (M_ * H_ * 96 + M_ * 32 + 255) / 256;
    build_qckv<<<nb, 256, 0, stream>>>(qkvb, cosT, sinT, qb, kropeb);

    // up-projection: A = qkvb cols 3072..3583 (lda=3840), bf16 out, grid 40x16
    gemm256<true><<<dim3(NUP_ / 128, M_ / 256), 512, 0, stream>>>(qkvb + NQ_, wupT, upb, M_, NUP_, RK_, QKVP_);
    build_kvt<<<B_ * H_ * 32, 256, 0, stream>>>(upb, kropeb, kb, vtb);

    attn<<<256, 512, 0, stream>>>(qb, kb, vtb, po0, po1, pm0, pl0, pm1, pl1);
    attn_merge<<<(256 * 256 * 48) / 256, 256, 0, stream>>>(po0, po1, pm0, pl0, pm1, pl1, ao);

    // output projection: 256x128 GEMM, fp32 out, grid 16x16 = 256 blocks
    gemm256<false><<<dim3(E_ / 128, M_ / 256), 512, 0, stream>>>(ao, woutT, out, M_, E_, NQ_, NQ_);
}